// Round 1
// baseline (5703.074 us; speedup 1.0000x reference)
//
#include <hip/hip_runtime.h>

// Problem constants (match reference setup_inputs)
constexpr int ND   = 50000;
constexpr int NZ   = 20000;
constexpr int HID  = 128;
constexpr int OUTD = 64;
constexpr int E    = 1000000;

static inline int ceil_div(int a, int b) { return (a + b - 1) / b; }

// ---------------------------------------------------------------------------
// Gather rows: out[i][:] = emb[idx[i]][:]   (128 floats per row, float4 x 32)
// ---------------------------------------------------------------------------
__global__ __launch_bounds__(256) void gather_rows(
    const float* __restrict__ emb, const int* __restrict__ idx,
    float* __restrict__ out, int n)
{
    int t = blockIdx.x * blockDim.x + threadIdx.x;
    int row = t >> 5;
    int c = (t & 31) * 4;
    if (row < n) {
        int s = idx[row];
        *reinterpret_cast<float4*>(out + (size_t)row * HID + c) =
            *reinterpret_cast<const float4*>(emb + (size_t)s * HID + c);
    }
}

// ---------------------------------------------------------------------------
// Scatter-add: for each edge e: S[dst[e]][:] += X[src[e]][:]; C[dst[e]] += 1
// One wave (64 lanes) per edge, 2 floats per lane.
// ---------------------------------------------------------------------------
__global__ __launch_bounds__(256) void scatter_kernel(
    const int* __restrict__ src, const int* __restrict__ dst,
    const float* __restrict__ X, float* __restrict__ S,
    float* __restrict__ C, int ne)
{
    int gtid = blockIdx.x * blockDim.x + threadIdx.x;
    int wave = gtid >> 6;
    int lane = threadIdx.x & 63;
    int nw = (gridDim.x * blockDim.x) >> 6;
    for (int e = wave; e < ne; e += nw) {
        int s = src[e];
        int d = dst[e];
        float2 v = *reinterpret_cast<const float2*>(X + (size_t)s * HID + lane * 2);
        float* p = S + (size_t)d * HID + lane * 2;
        atomicAdd(p, v.x);
        atomicAdd(p + 1, v.y);
        if (lane == 0) atomicAdd(C + d, 1.0f);
    }
}

// ---------------------------------------------------------------------------
// Fused SAGE compute per destination node:
//   mean = S[i]/max(C[i],1);  out = mean@Wl + bl + Xd[i]@Wr;  out /= max(||out||,1e-12)
//   H[i] = out  (or += out when ADD)
// Block = 256 threads, NB=8 nodes per block. GROUPS = 256/CO groups of CO
// threads; each group owns NPG = NB/GROUPS nodes; thread j in a group
// computes output column j for each of its group's nodes.
// ---------------------------------------------------------------------------
template <int CO, bool ADD>
__global__ __launch_bounds__(256) void sage_kernel(
    const float* __restrict__ S, const float* __restrict__ C,
    const float* __restrict__ Xd,
    const float* __restrict__ Wl, const float* __restrict__ bl,
    const float* __restrict__ Wr,
    float* __restrict__ H, int n)
{
    constexpr int NB = 8;
    constexpr int GROUPS = 256 / CO;   // 2 (CO=128) or 4 (CO=64)
    constexpr int NPG = NB / GROUPS;   // 4 or 2

    __shared__ float sm[NB][HID];
    __shared__ float sx[NB][HID];
    __shared__ float red[4][NPG];

    const int tid = threadIdx.x;
    const int base = blockIdx.x * NB;

    // Load mean and root feats into LDS
    for (int t = tid; t < NB * HID; t += 256) {
        int r = t / HID, k = t % HID;
        int row = base + r;
        if (row < n) {
            float c = fmaxf(C[row], 1.0f);
            sm[r][k] = S[(size_t)row * HID + k] / c;
            sx[r][k] = Xd[(size_t)row * HID + k];
        } else {
            sm[r][k] = 0.f;
            sx[r][k] = 0.f;
        }
    }
    __syncthreads();

    const int g = tid / CO;
    const int j = tid % CO;

    float acc[NPG];
    const float bj = bl[j];
#pragma unroll
    for (int p = 0; p < NPG; ++p) acc[p] = bj;

    for (int k = 0; k < HID; ++k) {
        float wl = Wl[k * CO + j];
        float wr = Wr[k * CO + j];
#pragma unroll
        for (int p = 0; p < NPG; ++p) {
            int r = g * NPG + p;
            acc[p] = fmaf(sm[r][k], wl, fmaf(sx[r][k], wr, acc[p]));
        }
    }

    // L2 norm per node across the group's CO threads
    const int lane = tid & 63;
    const int wv = tid >> 6;
    float tot[NPG];
#pragma unroll
    for (int p = 0; p < NPG; ++p) {
        float v = acc[p] * acc[p];
#pragma unroll
        for (int off = 32; off > 0; off >>= 1)
            v += __shfl_xor(v, off, 64);
        tot[p] = v;  // valid for CO==64 (group == wave)
    }
    if constexpr (CO == 128) {
        if (lane == 0) {
#pragma unroll
            for (int p = 0; p < NPG; ++p) red[wv][p] = tot[p];
        }
        __syncthreads();
#pragma unroll
        for (int p = 0; p < NPG; ++p)
            tot[p] = red[g * 2][p] + red[g * 2 + 1][p];
    }

#pragma unroll
    for (int p = 0; p < NPG; ++p) {
        int row = base + g * NPG + p;
        if (row < n) {
            float o = acc[p] / fmaxf(sqrtf(tot[p]), 1e-12f);
            if (ADD) H[(size_t)row * CO + j] += o;
            else     H[(size_t)row * CO + j] = o;
        }
    }
}

// ---------------------------------------------------------------------------
// LayerNorm (optionally + ReLU), one wave per row, D/64 elements per lane
// ---------------------------------------------------------------------------
template <int D, bool RELU>
__global__ __launch_bounds__(256) void ln_kernel(
    const float* __restrict__ X, const float* __restrict__ gg,
    const float* __restrict__ bb, float* __restrict__ out, int n)
{
    constexpr int VPL = D / 64;
    int wid = (blockIdx.x * blockDim.x + threadIdx.x) >> 6;
    int lane = threadIdx.x & 63;
    if (wid >= n) return;

    float v[VPL], gv[VPL], bv[VPL];
    const float* xp = X + (size_t)wid * D + lane * VPL;
#pragma unroll
    for (int k = 0; k < VPL; ++k) {
        v[k] = xp[k];
        gv[k] = gg[lane * VPL + k];
        bv[k] = bb[lane * VPL + k];
    }
    float s = 0.f;
#pragma unroll
    for (int k = 0; k < VPL; ++k) s += v[k];
#pragma unroll
    for (int off = 32; off > 0; off >>= 1) s += __shfl_xor(s, off, 64);
    float m = s / D;
    float ss = 0.f;
#pragma unroll
    for (int k = 0; k < VPL; ++k) { float d = v[k] - m; ss += d * d; }
#pragma unroll
    for (int off = 32; off > 0; off >>= 1) ss += __shfl_xor(ss, off, 64);
    float rstd = rsqrtf(ss / D + 1e-5f);

    float* op = out + (size_t)wid * D + lane * VPL;
#pragma unroll
    for (int k = 0; k < VPL; ++k) {
        float y = gv[k] * (v[k] - m) * rstd + bv[k];
        if (RELU) y = fmaxf(y, 0.f);
        op[k] = y;
    }
}

// ---------------------------------------------------------------------------
extern "C" void kernel_launch(void* const* d_in, const int* in_sizes, int n_in,
                              void* d_out, int out_size, void* d_ws, size_t ws_size,
                              hipStream_t stream)
{
    const int*   x_drug   = (const int*)d_in[0];
    const int*   x_dis    = (const int*)d_in[1];
    const float* emb_drug = (const float*)d_in[2];
    const float* emb_dis  = (const float*)d_in[3];
    const int*   src_dd   = (const int*)d_in[4];
    const int*   dst_dd   = (const int*)d_in[5];
    const int*   src_td   = (const int*)d_in[6];
    const int*   dst_td   = (const int*)d_in[7];
    const int*   src_rd   = (const int*)d_in[8];
    const int*   dst_rd   = (const int*)d_in[9];
    const float* Wl0_dd = (const float*)d_in[10];
    const float* bl0_dd = (const float*)d_in[11];
    const float* Wr0_dd = (const float*)d_in[12];
    const float* Wl0_td = (const float*)d_in[13];
    const float* bl0_td = (const float*)d_in[14];
    const float* Wr0_td = (const float*)d_in[15];
    const float* Wl0_rd = (const float*)d_in[16];
    const float* bl0_rd = (const float*)d_in[17];
    const float* Wr0_rd = (const float*)d_in[18];
    const float* Wl1_dd = (const float*)d_in[19];
    const float* bl1_dd = (const float*)d_in[20];
    const float* Wr1_dd = (const float*)d_in[21];
    const float* Wl1_td = (const float*)d_in[22];
    const float* bl1_td = (const float*)d_in[23];
    const float* Wr1_td = (const float*)d_in[24];
    const float* Wl1_rd = (const float*)d_in[25];
    const float* bl1_rd = (const float*)d_in[26];
    const float* Wr1_rd = (const float*)d_in[27];
    const float* g0_drug = (const float*)d_in[28];
    const float* b0_drug = (const float*)d_in[29];
    const float* g0_dis  = (const float*)d_in[30];
    const float* b0_dis  = (const float*)d_in[31];
    const float* g1_drug = (const float*)d_in[32];
    const float* b1_drug = (const float*)d_in[33];
    const float* g1_dis  = (const float*)d_in[34];
    const float* b1_dis  = (const float*)d_in[35];

    // Workspace layout (floats)
    float* ws = (float*)d_ws;
    float* hd0 = ws;                        // ND*HID
    float* hz0 = hd0 + (size_t)ND * HID;    // NZ*HID
    float* sA  = hz0 + (size_t)NZ * HID;    // ND*HID  (dd aggregation)
    float* sB  = sA  + (size_t)ND * HID;    // ND*HID  (rd aggregation)
    float* sC  = sB  + (size_t)ND * HID;    // NZ*HID  (td aggregation)
    float* cA  = sC  + (size_t)NZ * HID;    // ND
    float* cB  = cA  + ND;                  // ND
    float* cC  = cB  + ND;                  // NZ
    float* hd1 = cC  + NZ;                  // ND*HID
    float* hz1 = hd1 + (size_t)ND * HID;    // NZ*HID

    const size_t zero_bytes =
        ((size_t)ND * HID * 2 + (size_t)NZ * HID + 2 * (size_t)ND + NZ) * sizeof(float);

    float* outD = (float*)d_out;
    float* outZ = outD + (size_t)ND * OUTD;

    const int SC_GRID = 2048;

    // ---------------- layer 0 ----------------
    hipMemsetAsync(sA, 0, zero_bytes, stream);

    gather_rows<<<ceil_div(ND * 32, 256), 256, 0, stream>>>(emb_drug, x_drug, hd0, ND);
    gather_rows<<<ceil_div(NZ * 32, 256), 256, 0, stream>>>(emb_dis, x_dis, hz0, NZ);

    scatter_kernel<<<SC_GRID, 256, 0, stream>>>(src_dd, dst_dd, hd0, sA, cA, E);
    scatter_kernel<<<SC_GRID, 256, 0, stream>>>(src_rd, dst_rd, hz0, sB, cB, E);
    scatter_kernel<<<SC_GRID, 256, 0, stream>>>(src_td, dst_td, hd0, sC, cC, E);

    sage_kernel<128, false><<<ceil_div(ND, 8), 256, 0, stream>>>(sA, cA, hd0, Wl0_dd, bl0_dd, Wr0_dd, hd1, ND);
    sage_kernel<128, true ><<<ceil_div(ND, 8), 256, 0, stream>>>(sB, cB, hd0, Wl0_rd, bl0_rd, Wr0_rd, hd1, ND);
    sage_kernel<128, false><<<ceil_div(NZ, 8), 256, 0, stream>>>(sC, cC, hz0, Wl0_td, bl0_td, Wr0_td, hz1, NZ);

    ln_kernel<128, true><<<ceil_div(ND, 4), 256, 0, stream>>>(hd1, g0_drug, b0_drug, hd1, ND);
    ln_kernel<128, true><<<ceil_div(NZ, 4), 256, 0, stream>>>(hz1, g0_dis, b0_dis, hz1, NZ);

    // ---------------- layer 1 ----------------
    hipMemsetAsync(sA, 0, zero_bytes, stream);

    scatter_kernel<<<SC_GRID, 256, 0, stream>>>(src_dd, dst_dd, hd1, sA, cA, E);
    scatter_kernel<<<SC_GRID, 256, 0, stream>>>(src_rd, dst_rd, hz1, sB, cB, E);
    scatter_kernel<<<SC_GRID, 256, 0, stream>>>(src_td, dst_td, hd1, sC, cC, E);

    sage_kernel<64, false><<<ceil_div(ND, 8), 256, 0, stream>>>(sA, cA, hd1, Wl1_dd, bl1_dd, Wr1_dd, outD, ND);
    sage_kernel<64, true ><<<ceil_div(ND, 8), 256, 0, stream>>>(sB, cB, hd1, Wl1_rd, bl1_rd, Wr1_rd, outD, ND);
    sage_kernel<64, false><<<ceil_div(NZ, 8), 256, 0, stream>>>(sC, cC, hz1, Wl1_td, bl1_td, Wr1_td, outZ, NZ);

    ln_kernel<64, false><<<ceil_div(ND, 4), 256, 0, stream>>>(outD, g1_drug, b1_drug, outD, ND);
    ln_kernel<64, false><<<ceil_div(NZ, 4), 256, 0, stream>>>(outZ, g1_dis, b1_dis, outZ, NZ);
}

// Round 2
// 1587.811 us; speedup vs baseline: 3.5918x; 3.5918x over previous
//
#include <hip/hip_runtime.h>

// Problem constants (match reference setup_inputs)
constexpr int ND   = 50000;
constexpr int NZ   = 20000;
constexpr int HID  = 128;
constexpr int OUTD = 64;
constexpr int E    = 1000000;

static inline int ceil_div(int a, int b) { return (a + b - 1) / b; }

// ---------------------------------------------------------------------------
// Gather rows: out[i][:] = emb[idx[i]][:]   (128 floats per row, float4 x 32)
// ---------------------------------------------------------------------------
__global__ __launch_bounds__(256) void gather_rows(
    const float* __restrict__ emb, const int* __restrict__ idx,
    float* __restrict__ out, int n)
{
    int t = blockIdx.x * blockDim.x + threadIdx.x;
    int row = t >> 5;
    int c = (t & 31) * 4;
    if (row < n) {
        int s = idx[row];
        *reinterpret_cast<float4*>(out + (size_t)row * HID + c) =
            *reinterpret_cast<const float4*>(emb + (size_t)s * HID + c);
    }
}

// ---------------------------------------------------------------------------
// CSR build: histogram -> single-block exclusive scan -> fill
// ---------------------------------------------------------------------------
__global__ __launch_bounds__(256) void hist_kernel(
    const int* __restrict__ dst, int* __restrict__ cnt, int ne)
{
    int stride = gridDim.x * blockDim.x;
    for (int e = blockIdx.x * blockDim.x + threadIdx.x; e < ne; e += stride)
        atomicAdd(&cnt[dst[e]], 1);
}

__global__ __launch_bounds__(1024) void scan_kernel(
    const int* __restrict__ cnt, int* __restrict__ offs,
    int* __restrict__ cursor, int n)
{
    __shared__ int part[1024];
    const int tid = threadIdx.x;
    const int chunk = (n + 1023) / 1024;
    const int lo = min(tid * chunk, n);
    const int hi = min(lo + chunk, n);

    int s = 0;
    for (int i = lo; i < hi; ++i) s += cnt[i];
    part[tid] = s;
    __syncthreads();
#pragma unroll
    for (int off = 1; off < 1024; off <<= 1) {
        int v = (tid >= off) ? part[tid - off] : 0;
        __syncthreads();
        part[tid] += v;
        __syncthreads();
    }
    int run = (tid == 0) ? 0 : part[tid - 1];
    for (int i = lo; i < hi; ++i) {
        offs[i] = run;
        cursor[i] = run;
        run += cnt[i];
    }
    if (tid == 1023) offs[n] = part[1023];
}

__global__ __launch_bounds__(256) void fill_kernel(
    const int* __restrict__ src, const int* __restrict__ dst,
    int* __restrict__ cursor, int* __restrict__ col, int ne)
{
    int stride = gridDim.x * blockDim.x;
    for (int e = blockIdx.x * blockDim.x + threadIdx.x; e < ne; e += stride) {
        int p = atomicAdd(&cursor[dst[e]], 1);
        col[p] = src[e];
    }
}

// ---------------------------------------------------------------------------
// CSR mean-aggregation: one wave per destination node, 2 floats/lane.
//   M[i][:] = sum_{e in offs[i]..offs[i+1]} X[col[e]][:] / max(deg,1)
// ---------------------------------------------------------------------------
__global__ __launch_bounds__(256) void agg_mean(
    const int* __restrict__ offs, const int* __restrict__ col,
    const float* __restrict__ X, float* __restrict__ M, int n)
{
    int wid = (blockIdx.x * blockDim.x + threadIdx.x) >> 6;
    int lane = threadIdx.x & 63;
    if (wid >= n) return;

    const int start = offs[wid];
    const int end = offs[wid + 1];
    float2 a0 = {0.f, 0.f}, a1 = {0.f, 0.f};
    int e = start;
    for (; e + 1 < end; e += 2) {
        int s0 = col[e], s1 = col[e + 1];
        float2 v0 = *reinterpret_cast<const float2*>(X + (size_t)s0 * HID + lane * 2);
        float2 v1 = *reinterpret_cast<const float2*>(X + (size_t)s1 * HID + lane * 2);
        a0.x += v0.x; a0.y += v0.y;
        a1.x += v1.x; a1.y += v1.y;
    }
    if (e < end) {
        int s0 = col[e];
        float2 v0 = *reinterpret_cast<const float2*>(X + (size_t)s0 * HID + lane * 2);
        a0.x += v0.x; a0.y += v0.y;
    }
    float inv = 1.0f / (float)max(end - start, 1);
    float2 out;
    out.x = (a0.x + a1.x) * inv;
    out.y = (a0.y + a1.y) * inv;
    *reinterpret_cast<float2*>(M + (size_t)wid * HID + lane * 2) = out;
}

// ---------------------------------------------------------------------------
// Fused SAGE compute per destination node (M is already the mean):
//   out = M[i]@Wl + bl + Xd[i]@Wr;  out /= max(||out||,1e-12);  H[i] =/+= out
// ---------------------------------------------------------------------------
template <int CO, bool ADD>
__global__ __launch_bounds__(256) void sage_kernel(
    const float* __restrict__ M,
    const float* __restrict__ Xd,
    const float* __restrict__ Wl, const float* __restrict__ bl,
    const float* __restrict__ Wr,
    float* __restrict__ H, int n)
{
    constexpr int NB = 8;
    constexpr int GROUPS = 256 / CO;   // 2 (CO=128) or 4 (CO=64)
    constexpr int NPG = NB / GROUPS;   // 4 or 2

    __shared__ float sm[NB][HID];
    __shared__ float sx[NB][HID];
    __shared__ float red[4][NPG];

    const int tid = threadIdx.x;
    const int base = blockIdx.x * NB;

    for (int t = tid; t < NB * HID; t += 256) {
        int r = t / HID, k = t % HID;
        int row = base + r;
        if (row < n) {
            sm[r][k] = M[(size_t)row * HID + k];
            sx[r][k] = Xd[(size_t)row * HID + k];
        } else {
            sm[r][k] = 0.f;
            sx[r][k] = 0.f;
        }
    }
    __syncthreads();

    const int g = tid / CO;
    const int j = tid % CO;

    float acc[NPG];
    const float bj = bl[j];
#pragma unroll
    for (int p = 0; p < NPG; ++p) acc[p] = bj;

    for (int k = 0; k < HID; ++k) {
        float wl = Wl[k * CO + j];
        float wr = Wr[k * CO + j];
#pragma unroll
        for (int p = 0; p < NPG; ++p) {
            int r = g * NPG + p;
            acc[p] = fmaf(sm[r][k], wl, fmaf(sx[r][k], wr, acc[p]));
        }
    }

    const int lane = tid & 63;
    const int wv = tid >> 6;
    float tot[NPG];
#pragma unroll
    for (int p = 0; p < NPG; ++p) {
        float v = acc[p] * acc[p];
#pragma unroll
        for (int off = 32; off > 0; off >>= 1)
            v += __shfl_xor(v, off, 64);
        tot[p] = v;  // valid for CO==64 (group == wave)
    }
    if constexpr (CO == 128) {
        if (lane == 0) {
#pragma unroll
            for (int p = 0; p < NPG; ++p) red[wv][p] = tot[p];
        }
        __syncthreads();
#pragma unroll
        for (int p = 0; p < NPG; ++p)
            tot[p] = red[g * 2][p] + red[g * 2 + 1][p];
    }

#pragma unroll
    for (int p = 0; p < NPG; ++p) {
        int row = base + g * NPG + p;
        if (row < n) {
            float o = acc[p] / fmaxf(sqrtf(tot[p]), 1e-12f);
            if (ADD) H[(size_t)row * CO + j] += o;
            else     H[(size_t)row * CO + j] = o;
        }
    }
}

// ---------------------------------------------------------------------------
// LayerNorm (optionally + ReLU), one wave per row
// ---------------------------------------------------------------------------
template <int D, bool RELU>
__global__ __launch_bounds__(256) void ln_kernel(
    const float* __restrict__ X, const float* __restrict__ gg,
    const float* __restrict__ bb, float* __restrict__ out, int n)
{
    constexpr int VPL = D / 64;
    int wid = (blockIdx.x * blockDim.x + threadIdx.x) >> 6;
    int lane = threadIdx.x & 63;
    if (wid >= n) return;

    float v[VPL], gv[VPL], bv[VPL];
    const float* xp = X + (size_t)wid * D + lane * VPL;
#pragma unroll
    for (int k = 0; k < VPL; ++k) {
        v[k] = xp[k];
        gv[k] = gg[lane * VPL + k];
        bv[k] = bb[lane * VPL + k];
    }
    float s = 0.f;
#pragma unroll
    for (int k = 0; k < VPL; ++k) s += v[k];
#pragma unroll
    for (int off = 32; off > 0; off >>= 1) s += __shfl_xor(s, off, 64);
    float m = s / D;
    float ss = 0.f;
#pragma unroll
    for (int k = 0; k < VPL; ++k) { float d = v[k] - m; ss += d * d; }
#pragma unroll
    for (int off = 32; off > 0; off >>= 1) ss += __shfl_xor(ss, off, 64);
    float rstd = rsqrtf(ss / D + 1e-5f);

    float* op = out + (size_t)wid * D + lane * VPL;
#pragma unroll
    for (int k = 0; k < VPL; ++k) {
        float y = gv[k] * (v[k] - m) * rstd + bv[k];
        if (RELU) y = fmaxf(y, 0.f);
        op[k] = y;
    }
}

// ---------------------------------------------------------------------------
extern "C" void kernel_launch(void* const* d_in, const int* in_sizes, int n_in,
                              void* d_out, int out_size, void* d_ws, size_t ws_size,
                              hipStream_t stream)
{
    const int*   x_drug   = (const int*)d_in[0];
    const int*   x_dis    = (const int*)d_in[1];
    const float* emb_drug = (const float*)d_in[2];
    const float* emb_dis  = (const float*)d_in[3];
    const int*   src_dd   = (const int*)d_in[4];
    const int*   dst_dd   = (const int*)d_in[5];
    const int*   src_td   = (const int*)d_in[6];
    const int*   dst_td   = (const int*)d_in[7];
    const int*   src_rd   = (const int*)d_in[8];
    const int*   dst_rd   = (const int*)d_in[9];
    const float* Wl0_dd = (const float*)d_in[10];
    const float* bl0_dd = (const float*)d_in[11];
    const float* Wr0_dd = (const float*)d_in[12];
    const float* Wl0_td = (const float*)d_in[13];
    const float* bl0_td = (const float*)d_in[14];
    const float* Wr0_td = (const float*)d_in[15];
    const float* Wl0_rd = (const float*)d_in[16];
    const float* bl0_rd = (const float*)d_in[17];
    const float* Wr0_rd = (const float*)d_in[18];
    const float* Wl1_dd = (const float*)d_in[19];
    const float* bl1_dd = (const float*)d_in[20];
    const float* Wr1_dd = (const float*)d_in[21];
    const float* Wl1_td = (const float*)d_in[22];
    const float* bl1_td = (const float*)d_in[23];
    const float* Wr1_td = (const float*)d_in[24];
    const float* Wl1_rd = (const float*)d_in[25];
    const float* bl1_rd = (const float*)d_in[26];
    const float* Wr1_rd = (const float*)d_in[27];
    const float* g0_drug = (const float*)d_in[28];
    const float* b0_drug = (const float*)d_in[29];
    const float* g0_dis  = (const float*)d_in[30];
    const float* b0_dis  = (const float*)d_in[31];
    const float* g1_drug = (const float*)d_in[32];
    const float* b1_drug = (const float*)d_in[33];
    const float* g1_dis  = (const float*)d_in[34];
    const float* b1_dis  = (const float*)d_in[35];

    // Workspace layout (4-byte units)
    float* ws = (float*)d_ws;
    float* hd0  = ws;                        // ND*HID
    float* hz0  = hd0  + (size_t)ND * HID;   // NZ*HID
    float* hd1  = hz0  + (size_t)NZ * HID;   // ND*HID
    float* hz1  = hd1  + (size_t)ND * HID;   // NZ*HID
    float* mean = hz1  + (size_t)NZ * HID;   // ND*HID (shared, sequential use)
    int* ip      = (int*)(mean + (size_t)ND * HID);
    int* offs_dd = ip;                 ip += ND + 1;
    int* offs_rd = ip;                 ip += ND + 1;
    int* offs_td = ip;                 ip += NZ + 1;
    int* col_dd  = ip;                 ip += E;
    int* col_rd  = ip;                 ip += E;
    int* col_td  = ip;                 ip += E;
    int* cursor  = ip;                 ip += ND + 1;   // shared counts/cursor

    float* outD = (float*)d_out;
    float* outZ = outD + (size_t)ND * OUTD;

    // ---------------- input gathers ----------------
    gather_rows<<<ceil_div(ND * 32, 256), 256, 0, stream>>>(emb_drug, x_drug, hd0, ND);
    gather_rows<<<ceil_div(NZ * 32, 256), 256, 0, stream>>>(emb_dis, x_dis, hz0, NZ);

    // ---------------- CSR builds (reused by both layers) ----------------
    // dd: dst in [0,ND)
    hipMemsetAsync(cursor, 0, (ND + 1) * sizeof(int), stream);
    hist_kernel<<<1024, 256, 0, stream>>>(dst_dd, cursor, E);
    scan_kernel<<<1, 1024, 0, stream>>>(cursor, offs_dd, cursor, ND);
    fill_kernel<<<1024, 256, 0, stream>>>(src_dd, dst_dd, cursor, col_dd, E);
    // rd: dst in [0,ND)
    hipMemsetAsync(cursor, 0, (ND + 1) * sizeof(int), stream);
    hist_kernel<<<1024, 256, 0, stream>>>(dst_rd, cursor, E);
    scan_kernel<<<1, 1024, 0, stream>>>(cursor, offs_rd, cursor, ND);
    fill_kernel<<<1024, 256, 0, stream>>>(src_rd, dst_rd, cursor, col_rd, E);
    // td: dst in [0,NZ)
    hipMemsetAsync(cursor, 0, (NZ + 1) * sizeof(int), stream);
    hist_kernel<<<1024, 256, 0, stream>>>(dst_td, cursor, E);
    scan_kernel<<<1, 1024, 0, stream>>>(cursor, offs_td, cursor, NZ);
    fill_kernel<<<1024, 256, 0, stream>>>(src_td, dst_td, cursor, col_td, E);

    // ---------------- layer 0 ----------------
    agg_mean<<<ceil_div(ND * 64, 256), 256, 0, stream>>>(offs_dd, col_dd, hd0, mean, ND);
    sage_kernel<128, false><<<ceil_div(ND, 8), 256, 0, stream>>>(mean, hd0, Wl0_dd, bl0_dd, Wr0_dd, hd1, ND);

    agg_mean<<<ceil_div(ND * 64, 256), 256, 0, stream>>>(offs_rd, col_rd, hz0, mean, ND);
    sage_kernel<128, true ><<<ceil_div(ND, 8), 256, 0, stream>>>(mean, hd0, Wl0_rd, bl0_rd, Wr0_rd, hd1, ND);

    agg_mean<<<ceil_div(NZ * 64, 256), 256, 0, stream>>>(offs_td, col_td, hd0, mean, NZ);
    sage_kernel<128, false><<<ceil_div(NZ, 8), 256, 0, stream>>>(mean, hz0, Wl0_td, bl0_td, Wr0_td, hz1, NZ);

    ln_kernel<128, true><<<ceil_div(ND, 4), 256, 0, stream>>>(hd1, g0_drug, b0_drug, hd1, ND);
    ln_kernel<128, true><<<ceil_div(NZ, 4), 256, 0, stream>>>(hz1, g0_dis, b0_dis, hz1, NZ);

    // ---------------- layer 1 ----------------
    agg_mean<<<ceil_div(ND * 64, 256), 256, 0, stream>>>(offs_dd, col_dd, hd1, mean, ND);
    sage_kernel<64, false><<<ceil_div(ND, 8), 256, 0, stream>>>(mean, hd1, Wl1_dd, bl1_dd, Wr1_dd, outD, ND);

    agg_mean<<<ceil_div(ND * 64, 256), 256, 0, stream>>>(offs_rd, col_rd, hz1, mean, ND);
    sage_kernel<64, true ><<<ceil_div(ND, 8), 256, 0, stream>>>(mean, hd1, Wl1_rd, bl1_rd, Wr1_rd, outD, ND);

    agg_mean<<<ceil_div(NZ * 64, 256), 256, 0, stream>>>(offs_td, col_td, hd1, mean, NZ);
    sage_kernel<64, false><<<ceil_div(NZ, 8), 256, 0, stream>>>(mean, hz1, Wl1_td, bl1_td, Wr1_td, outZ, NZ);

    ln_kernel<64, false><<<ceil_div(ND, 4), 256, 0, stream>>>(outD, g1_drug, b1_drug, outD, ND);
    ln_kernel<64, false><<<ceil_div(NZ, 4), 256, 0, stream>>>(outZ, g1_dis, b1_dis, outZ, NZ);
}

// Round 3
// 1180.162 us; speedup vs baseline: 4.8324x; 1.3454x over previous
//
#include <hip/hip_runtime.h>

// Problem constants (match reference setup_inputs)
constexpr int ND   = 50000;
constexpr int NZ   = 20000;
constexpr int HID  = 128;
constexpr int OUTD = 64;
constexpr int E    = 1000000;

static inline int ceil_div(int a, int b) { return (a + b - 1) / b; }

typedef __bf16 bf16x8 __attribute__((ext_vector_type(8)));
typedef float  f32x4  __attribute__((ext_vector_type(4)));

__device__ __forceinline__ float bf2f(unsigned short b) {
    return __uint_as_float(((unsigned int)b) << 16);
}
__device__ __forceinline__ unsigned short f2bf(float f) {
    unsigned int u = __float_as_uint(f);
    unsigned int r = (u + 0x7fffu + ((u >> 16) & 1u)) >> 16;
    return (unsigned short)r;
}

// ---------------------------------------------------------------------------
// Gather rows to bf16: out[i][:] = bf16(emb[idx[i]][:])
// ---------------------------------------------------------------------------
__global__ __launch_bounds__(256) void gather_bf16(
    const float* __restrict__ emb, const int* __restrict__ idx,
    unsigned short* __restrict__ out, int n)
{
    int t = blockIdx.x * blockDim.x + threadIdx.x;
    int row = t >> 5;
    int c = (t & 31) * 4;
    if (row < n) {
        int s = idx[row];
        float4 v = *reinterpret_cast<const float4*>(emb + (size_t)s * HID + c);
        ushort4 o;
        o.x = f2bf(v.x); o.y = f2bf(v.y); o.z = f2bf(v.z); o.w = f2bf(v.w);
        *reinterpret_cast<ushort4*>(out + (size_t)row * HID + c) = o;
    }
}

// ---------------------------------------------------------------------------
// CSR build: histogram -> single-block exclusive scan -> fill
// ---------------------------------------------------------------------------
__global__ __launch_bounds__(256) void hist_kernel(
    const int* __restrict__ dst, int* __restrict__ cnt, int ne)
{
    int stride = gridDim.x * blockDim.x;
    for (int e = blockIdx.x * blockDim.x + threadIdx.x; e < ne; e += stride)
        atomicAdd(&cnt[dst[e]], 1);
}

__global__ __launch_bounds__(1024) void scan_kernel(
    const int* __restrict__ cnt, int* __restrict__ offs,
    int* __restrict__ cursor, int n)
{
    __shared__ int part[1024];
    const int tid = threadIdx.x;
    const int chunk = (n + 1023) / 1024;
    const int lo = min(tid * chunk, n);
    const int hi = min(lo + chunk, n);

    int s = 0;
    for (int i = lo; i < hi; ++i) s += cnt[i];
    part[tid] = s;
    __syncthreads();
#pragma unroll
    for (int off = 1; off < 1024; off <<= 1) {
        int v = (tid >= off) ? part[tid - off] : 0;
        __syncthreads();
        part[tid] += v;
        __syncthreads();
    }
    int run = (tid == 0) ? 0 : part[tid - 1];
    for (int i = lo; i < hi; ++i) {
        offs[i] = run;
        cursor[i] = run;
        run += cnt[i];
    }
    if (tid == 1023) offs[n] = part[1023];
}

__global__ __launch_bounds__(256) void fill_kernel(
    const int* __restrict__ src, const int* __restrict__ dst,
    int* __restrict__ cursor, int* __restrict__ col, int ne)
{
    int stride = gridDim.x * blockDim.x;
    for (int e = blockIdx.x * blockDim.x + threadIdx.x; e < ne; e += stride) {
        int p = atomicAdd(&cursor[dst[e]], 1);
        col[p] = src[e];
    }
}

// ---------------------------------------------------------------------------
// CSR mean-aggregation (bf16 in, bf16 out): one wave per destination node,
// 2 cols per lane (uint = 2 bf16), fp32 accumulate.
// ---------------------------------------------------------------------------
__global__ __launch_bounds__(256) void agg_mean_bf16(
    const int* __restrict__ offs, const int* __restrict__ col,
    const unsigned short* __restrict__ X, unsigned short* __restrict__ M, int n)
{
    int wid = (blockIdx.x * blockDim.x + threadIdx.x) >> 6;
    int lane = threadIdx.x & 63;
    if (wid >= n) return;

    const int start = offs[wid];
    const int end = offs[wid + 1];
    float a0x = 0.f, a0y = 0.f, a1x = 0.f, a1y = 0.f;
    int e = start;
    for (; e + 1 < end; e += 2) {
        int s0 = col[e], s1 = col[e + 1];
        unsigned int v0 = *reinterpret_cast<const unsigned int*>(X + (size_t)s0 * HID + lane * 2);
        unsigned int v1 = *reinterpret_cast<const unsigned int*>(X + (size_t)s1 * HID + lane * 2);
        a0x += bf2f((unsigned short)(v0 & 0xffffu));
        a0y += bf2f((unsigned short)(v0 >> 16));
        a1x += bf2f((unsigned short)(v1 & 0xffffu));
        a1y += bf2f((unsigned short)(v1 >> 16));
    }
    if (e < end) {
        int s0 = col[e];
        unsigned int v0 = *reinterpret_cast<const unsigned int*>(X + (size_t)s0 * HID + lane * 2);
        a0x += bf2f((unsigned short)(v0 & 0xffffu));
        a0y += bf2f((unsigned short)(v0 >> 16));
    }
    float inv = 1.0f / (float)max(end - start, 1);
    unsigned int o = (unsigned int)f2bf((a0x + a1x) * inv)
                   | ((unsigned int)f2bf((a0y + a1y) * inv) << 16);
    *reinterpret_cast<unsigned int*>(M + (size_t)wid * HID + lane * 2) = o;
}

// ---------------------------------------------------------------------------
// Weight prep: Wt[j][k] = bf16( k<128 ? Wl[k][j] : Wr[k-128][j] ), j in [0,CO)
// ---------------------------------------------------------------------------
__global__ __launch_bounds__(256) void prep_w(
    const float* __restrict__ Wl, const float* __restrict__ Wr,
    unsigned short* __restrict__ Wt, int CO)
{
    int idx = blockIdx.x * 256 + threadIdx.x;   // CO*256 total
    int j = idx >> 8;
    int k = idx & 255;
    float v = (k < HID) ? Wl[k * CO + j] : Wr[(k - HID) * CO + j];
    Wt[(size_t)j * 256 + k] = f2bf(v);
}

// ---------------------------------------------------------------------------
// MFMA SAGE: out = [mean | x] @ [Wl;Wr] + bl, then L2-normalize, write/add.
// Block = 256 threads = 4 waves; each wave computes a 16-node x CO tile.
// K = 256 (128 mean + 128 x). A,B fragments per mfma_f32_16x16x32_bf16:
//   A: lane holds A[lane&15][kstep*32 + (lane>>4)*8 + i]
//   B: lane holds B[kstep*32 + (lane>>4)*8 + i][lane&15]
//   C/D: col = lane&15, row = (lane>>4)*4 + reg   [verified m89]
// ---------------------------------------------------------------------------
template <int CO, bool ADD>
__global__ __launch_bounds__(256) void sage_mfma(
    const unsigned short* __restrict__ Mb,   // [n][128] bf16 mean
    const unsigned short* __restrict__ Xb,   // [n][128] bf16 root feats
    const unsigned short* __restrict__ Wt,   // [CO][256] bf16
    const float* __restrict__ bl,            // [CO]
    float* __restrict__ H, int n)
{
    constexpr int NT = CO / 16;
    const int wave = threadIdx.x >> 6;
    const int lane = threadIdx.x & 63;
    const int r16 = lane & 15;
    const int chunk = lane >> 4;          // 0..3
    const int rowbase = blockIdx.x * 64 + wave * 16;

    const int arow = min(rowbase + r16, n - 1);
    const unsigned short* mrow = Mb + (size_t)arow * HID;
    const unsigned short* xrow = Xb + (size_t)arow * HID;

    bf16x8 a[8];
#pragma unroll
    for (int s = 0; s < 4; ++s)
        a[s] = *reinterpret_cast<const bf16x8*>(mrow + s * 32 + chunk * 8);
#pragma unroll
    for (int s = 0; s < 4; ++s)
        a[4 + s] = *reinterpret_cast<const bf16x8*>(xrow + s * 32 + chunk * 8);

    f32x4 acc[NT];
#pragma unroll
    for (int t = 0; t < NT; ++t) acc[t] = f32x4{0.f, 0.f, 0.f, 0.f};

#pragma unroll
    for (int t = 0; t < NT; ++t) {
        const unsigned short* wr_ = Wt + (size_t)(t * 16 + r16) * 256;
#pragma unroll
        for (int s = 0; s < 8; ++s) {
            bf16x8 b = *reinterpret_cast<const bf16x8*>(wr_ + s * 32 + chunk * 8);
            acc[t] = __builtin_amdgcn_mfma_f32_16x16x32_bf16(a[s], b, acc[t], 0, 0, 0);
        }
    }

    // bias + L2-norm. Node handled by this lane group: rowbase + chunk*4 + r.
    float bias[NT];
#pragma unroll
    for (int t = 0; t < NT; ++t) bias[t] = bl[t * 16 + r16];

    float bacc[NT][4];
    float ss[4] = {0.f, 0.f, 0.f, 0.f};
#pragma unroll
    for (int t = 0; t < NT; ++t) {
#pragma unroll
        for (int r = 0; r < 4; ++r) {
            float v = acc[t][r] + bias[t];
            bacc[t][r] = v;
            ss[r] += v * v;
        }
    }
#pragma unroll
    for (int r = 0; r < 4; ++r) {
#pragma unroll
        for (int m = 1; m < 16; m <<= 1)
            ss[r] += __shfl_xor(ss[r], m, 64);
    }

#pragma unroll
    for (int r = 0; r < 4; ++r) {
        int node = rowbase + chunk * 4 + r;
        if (node < n) {
            float inv = 1.0f / fmaxf(sqrtf(ss[r]), 1e-12f);
#pragma unroll
            for (int t = 0; t < NT; ++t) {
                float o = bacc[t][r] * inv;
                float* p = H + (size_t)node * CO + t * 16 + r16;
                if (ADD) *p += o;
                else     *p = o;
            }
        }
    }
}

// ---------------------------------------------------------------------------
// LayerNorm (+optional ReLU), one wave per row; fp32 in; bf16 or fp32 out.
// ---------------------------------------------------------------------------
template <int D, bool RELU, bool OUTBF>
__global__ __launch_bounds__(256) void ln_kernel(
    const float* __restrict__ X, const float* __restrict__ gg,
    const float* __restrict__ bb, void* __restrict__ outp, int n)
{
    constexpr int VPL = D / 64;
    int wid = (blockIdx.x * blockDim.x + threadIdx.x) >> 6;
    int lane = threadIdx.x & 63;
    if (wid >= n) return;

    float v[VPL], gv[VPL], bv[VPL];
    const float* xp = X + (size_t)wid * D + lane * VPL;
#pragma unroll
    for (int k = 0; k < VPL; ++k) {
        v[k] = xp[k];
        gv[k] = gg[lane * VPL + k];
        bv[k] = bb[lane * VPL + k];
    }
    float s = 0.f;
#pragma unroll
    for (int k = 0; k < VPL; ++k) s += v[k];
#pragma unroll
    for (int off = 32; off > 0; off >>= 1) s += __shfl_xor(s, off, 64);
    float m = s / D;
    float ss = 0.f;
#pragma unroll
    for (int k = 0; k < VPL; ++k) { float d = v[k] - m; ss += d * d; }
#pragma unroll
    for (int off = 32; off > 0; off >>= 1) ss += __shfl_xor(ss, off, 64);
    float rstd = rsqrtf(ss / D + 1e-5f);

    float y[VPL];
#pragma unroll
    for (int k = 0; k < VPL; ++k) {
        y[k] = gv[k] * (v[k] - m) * rstd + bv[k];
        if (RELU) y[k] = fmaxf(y[k], 0.f);
    }
    if (OUTBF) {
        unsigned short* op = (unsigned short*)outp + (size_t)wid * D + lane * VPL;
#pragma unroll
        for (int k = 0; k < VPL; ++k) op[k] = f2bf(y[k]);
    } else {
        float* op = (float*)outp + (size_t)wid * D + lane * VPL;
#pragma unroll
        for (int k = 0; k < VPL; ++k) op[k] = y[k];
    }
}

// ---------------------------------------------------------------------------
extern "C" void kernel_launch(void* const* d_in, const int* in_sizes, int n_in,
                              void* d_out, int out_size, void* d_ws, size_t ws_size,
                              hipStream_t stream)
{
    const int*   x_drug   = (const int*)d_in[0];
    const int*   x_dis    = (const int*)d_in[1];
    const float* emb_drug = (const float*)d_in[2];
    const float* emb_dis  = (const float*)d_in[3];
    const int*   src_dd   = (const int*)d_in[4];
    const int*   dst_dd   = (const int*)d_in[5];
    const int*   src_td   = (const int*)d_in[6];
    const int*   dst_td   = (const int*)d_in[7];
    const int*   src_rd   = (const int*)d_in[8];
    const int*   dst_rd   = (const int*)d_in[9];
    const float* Wl0_dd = (const float*)d_in[10];
    const float* bl0_dd = (const float*)d_in[11];
    const float* Wr0_dd = (const float*)d_in[12];
    const float* Wl0_td = (const float*)d_in[13];
    const float* bl0_td = (const float*)d_in[14];
    const float* Wr0_td = (const float*)d_in[15];
    const float* Wl0_rd = (const float*)d_in[16];
    const float* bl0_rd = (const float*)d_in[17];
    const float* Wr0_rd = (const float*)d_in[18];
    const float* Wl1_dd = (const float*)d_in[19];
    const float* bl1_dd = (const float*)d_in[20];
    const float* Wr1_dd = (const float*)d_in[21];
    const float* Wl1_td = (const float*)d_in[22];
    const float* bl1_td = (const float*)d_in[23];
    const float* Wr1_td = (const float*)d_in[24];
    const float* Wl1_rd = (const float*)d_in[25];
    const float* bl1_rd = (const float*)d_in[26];
    const float* Wr1_rd = (const float*)d_in[27];
    const float* g0_drug = (const float*)d_in[28];
    const float* b0_drug = (const float*)d_in[29];
    const float* g0_dis  = (const float*)d_in[30];
    const float* b0_dis  = (const float*)d_in[31];
    const float* g1_drug = (const float*)d_in[32];
    const float* b1_drug = (const float*)d_in[33];
    const float* g1_dis  = (const float*)d_in[34];
    const float* b1_dis  = (const float*)d_in[35];

    // ---------------- workspace layout ----------------
    char* wp = (char*)d_ws;
    auto alloc = [&](size_t bytes) { char* p = wp; wp += (bytes + 255) & ~size_t(255); return p; };

    unsigned short* hd0  = (unsigned short*)alloc((size_t)ND * HID * 2);
    unsigned short* hz0  = (unsigned short*)alloc((size_t)NZ * HID * 2);
    unsigned short* hd1b = (unsigned short*)alloc((size_t)ND * HID * 2);
    unsigned short* hz1b = (unsigned short*)alloc((size_t)NZ * HID * 2);
    unsigned short* meanb= (unsigned short*)alloc((size_t)ND * HID * 2);
    float* hd1f = (float*)alloc((size_t)ND * HID * 4);
    float* hz1f = (float*)alloc((size_t)NZ * HID * 4);
    unsigned short* Wt0_dd = (unsigned short*)alloc((size_t)HID * 256 * 2);
    unsigned short* Wt0_rd = (unsigned short*)alloc((size_t)HID * 256 * 2);
    unsigned short* Wt0_td = (unsigned short*)alloc((size_t)HID * 256 * 2);
    unsigned short* Wt1_dd = (unsigned short*)alloc((size_t)OUTD * 256 * 2);
    unsigned short* Wt1_rd = (unsigned short*)alloc((size_t)OUTD * 256 * 2);
    unsigned short* Wt1_td = (unsigned short*)alloc((size_t)OUTD * 256 * 2);
    int* offs_dd = (int*)alloc((ND + 1) * 4);
    int* offs_rd = (int*)alloc((ND + 1) * 4);
    int* offs_td = (int*)alloc((NZ + 1) * 4);
    int* col_dd  = (int*)alloc((size_t)E * 4);
    int* col_rd  = (int*)alloc((size_t)E * 4);
    int* col_td  = (int*)alloc((size_t)E * 4);
    int* cursor  = (int*)alloc((ND + 1) * 4);

    float* outD = (float*)d_out;
    float* outZ = outD + (size_t)ND * OUTD;

    // ---------------- input gathers + weight prep ----------------
    gather_bf16<<<ceil_div(ND * 32, 256), 256, 0, stream>>>(emb_drug, x_drug, hd0, ND);
    gather_bf16<<<ceil_div(NZ * 32, 256), 256, 0, stream>>>(emb_dis, x_dis, hz0, NZ);

    prep_w<<<HID, 256, 0, stream>>>(Wl0_dd, Wr0_dd, Wt0_dd, HID);
    prep_w<<<HID, 256, 0, stream>>>(Wl0_rd, Wr0_rd, Wt0_rd, HID);
    prep_w<<<HID, 256, 0, stream>>>(Wl0_td, Wr0_td, Wt0_td, HID);
    prep_w<<<OUTD, 256, 0, stream>>>(Wl1_dd, Wr1_dd, Wt1_dd, OUTD);
    prep_w<<<OUTD, 256, 0, stream>>>(Wl1_rd, Wr1_rd, Wt1_rd, OUTD);
    prep_w<<<OUTD, 256, 0, stream>>>(Wl1_td, Wr1_td, Wt1_td, OUTD);

    // ---------------- CSR builds (reused by both layers) ----------------
    hipMemsetAsync(cursor, 0, (ND + 1) * sizeof(int), stream);
    hist_kernel<<<1024, 256, 0, stream>>>(dst_dd, cursor, E);
    scan_kernel<<<1, 1024, 0, stream>>>(cursor, offs_dd, cursor, ND);
    fill_kernel<<<1024, 256, 0, stream>>>(src_dd, dst_dd, cursor, col_dd, E);

    hipMemsetAsync(cursor, 0, (ND + 1) * sizeof(int), stream);
    hist_kernel<<<1024, 256, 0, stream>>>(dst_rd, cursor, E);
    scan_kernel<<<1, 1024, 0, stream>>>(cursor, offs_rd, cursor, ND);
    fill_kernel<<<1024, 256, 0, stream>>>(src_rd, dst_rd, cursor, col_rd, E);

    hipMemsetAsync(cursor, 0, (NZ + 1) * sizeof(int), stream);
    hist_kernel<<<1024, 256, 0, stream>>>(dst_td, cursor, E);
    scan_kernel<<<1, 1024, 0, stream>>>(cursor, offs_td, cursor, NZ);
    fill_kernel<<<1024, 256, 0, stream>>>(src_td, dst_td, cursor, col_td, E);

    // ---------------- layer 0 ----------------
    agg_mean_bf16<<<ceil_div(ND * 64, 256), 256, 0, stream>>>(offs_dd, col_dd, hd0, meanb, ND);
    sage_mfma<HID, false><<<ceil_div(ND, 64), 256, 0, stream>>>(meanb, hd0, Wt0_dd, bl0_dd, hd1f, ND);

    agg_mean_bf16<<<ceil_div(ND * 64, 256), 256, 0, stream>>>(offs_rd, col_rd, hz0, meanb, ND);
    sage_mfma<HID, true ><<<ceil_div(ND, 64), 256, 0, stream>>>(meanb, hd0, Wt0_rd, bl0_rd, hd1f, ND);

    agg_mean_bf16<<<ceil_div(NZ * 64, 256), 256, 0, stream>>>(offs_td, col_td, hd0, meanb, NZ);
    sage_mfma<HID, false><<<ceil_div(NZ, 64), 256, 0, stream>>>(meanb, hz0, Wt0_td, bl0_td, hz1f, NZ);

    ln_kernel<HID, true, true><<<ceil_div(ND, 4), 256, 0, stream>>>(hd1f, g0_drug, b0_drug, hd1b, ND);
    ln_kernel<HID, true, true><<<ceil_div(NZ, 4), 256, 0, stream>>>(hz1f, g0_dis, b0_dis, hz1b, NZ);

    // ---------------- layer 1 ----------------
    agg_mean_bf16<<<ceil_div(ND * 64, 256), 256, 0, stream>>>(offs_dd, col_dd, hd1b, meanb, ND);
    sage_mfma<OUTD, false><<<ceil_div(ND, 64), 256, 0, stream>>>(meanb, hd1b, Wt1_dd, bl1_dd, outD, ND);

    agg_mean_bf16<<<ceil_div(ND * 64, 256), 256, 0, stream>>>(offs_rd, col_rd, hz1b, meanb, ND);
    sage_mfma<OUTD, true ><<<ceil_div(ND, 64), 256, 0, stream>>>(meanb, hd1b, Wt1_rd, bl1_rd, outD, ND);

    agg_mean_bf16<<<ceil_div(NZ * 64, 256), 256, 0, stream>>>(offs_td, col_td, hd1b, meanb, NZ);
    sage_mfma<OUTD, false><<<ceil_div(NZ, 64), 256, 0, stream>>>(meanb, hz1b, Wt1_td, bl1_td, outZ, NZ);

    ln_kernel<OUTD, false, false><<<ceil_div(ND, 4), 256, 0, stream>>>(outD, g1_drug, b1_drug, outD, ND);
    ln_kernel<OUTD, false, false><<<ceil_div(NZ, 4), 256, 0, stream>>>(outZ, g1_dis, b1_dis, outZ, NZ);
}

// Round 4
// 930.037 us; speedup vs baseline: 6.1321x; 1.2689x over previous
//
#include <hip/hip_runtime.h>

// Problem constants (match reference setup_inputs)
constexpr int ND   = 50000;
constexpr int NZ   = 20000;
constexpr int HID  = 128;
constexpr int OUTD = 64;
constexpr int E    = 1000000;

constexpr int SCAN_TILE = 1024;   // elements per scan block

static inline int ceil_div(int a, int b) { return (a + b - 1) / b; }

typedef __bf16 bf16x8 __attribute__((ext_vector_type(8)));
typedef float  f32x4  __attribute__((ext_vector_type(4)));

__device__ __forceinline__ float bf2f(unsigned short b) {
    return __uint_as_float(((unsigned int)b) << 16);
}
__device__ __forceinline__ unsigned short f2bf(float f) {
    unsigned int u = __float_as_uint(f);
    unsigned int r = (u + 0x7fffu + ((u >> 16) & 1u)) >> 16;
    return (unsigned short)r;
}

// ---------------------------------------------------------------------------
// Gather rows to bf16: out[i][:] = bf16(emb[idx[i]][:])
// ---------------------------------------------------------------------------
__global__ __launch_bounds__(256) void gather_bf16(
    const float* __restrict__ emb, const int* __restrict__ idx,
    unsigned short* __restrict__ out, int n)
{
    int t = blockIdx.x * blockDim.x + threadIdx.x;
    int row = t >> 5;
    int c = (t & 31) * 4;
    if (row < n) {
        int s = idx[row];
        float4 v = *reinterpret_cast<const float4*>(emb + (size_t)s * HID + c);
        ushort4 o;
        o.x = f2bf(v.x); o.y = f2bf(v.y); o.z = f2bf(v.z); o.w = f2bf(v.w);
        *reinterpret_cast<ushort4*>(out + (size_t)row * HID + c) = o;
    }
}

// ---------------------------------------------------------------------------
// CSR build: histogram -> 3-phase multi-block exclusive scan -> fill
// ---------------------------------------------------------------------------
__global__ __launch_bounds__(256) void hist_kernel(
    const int* __restrict__ dst, int* __restrict__ cnt, int ne)
{
    int stride = gridDim.x * blockDim.x;
    for (int e = blockIdx.x * blockDim.x + threadIdx.x; e < ne; e += stride)
        atomicAdd(&cnt[dst[e]], 1);
}

// Phase 1: per-tile sums
__global__ __launch_bounds__(256) void scan_part(
    const int* __restrict__ cnt, int* __restrict__ part, int n)
{
    __shared__ int red[256];
    int base = blockIdx.x * SCAN_TILE;
    int s = 0;
    for (int i = threadIdx.x; i < SCAN_TILE; i += 256) {
        int idx = base + i;
        if (idx < n) s += cnt[idx];
    }
    red[threadIdx.x] = s;
    __syncthreads();
#pragma unroll
    for (int off = 128; off > 0; off >>= 1) {
        if (threadIdx.x < off) red[threadIdx.x] += red[threadIdx.x + off];
        __syncthreads();
    }
    if (threadIdx.x == 0) part[blockIdx.x] = red[0];
}

// Phase 2: single-wave exclusive scan of <=64 partials; also writes offs[n]
__global__ __launch_bounds__(64) void scan_small(
    int* __restrict__ part, int* __restrict__ offs, int np, int n)
{
    int lane = threadIdx.x;
    int orig = (lane < np) ? part[lane] : 0;
    int v = orig;
#pragma unroll
    for (int off = 1; off < 64; off <<= 1) {
        int t = __shfl_up(v, off, 64);
        if (lane >= off) v += t;
    }
    if (lane < np) part[lane] = v - orig;   // exclusive
    if (lane == 63) offs[n] = v;            // total
}

// Phase 3: per-tile scan + base, writes offs and cursor
__global__ __launch_bounds__(256) void scan_write(
    const int* __restrict__ cnt, const int* __restrict__ part,
    int* __restrict__ offs, int* __restrict__ cursor, int n)
{
    __shared__ int sc[256];
    const int tid = threadIdx.x;
    const int tb = blockIdx.x * SCAN_TILE + tid * 4;
    int v[4];
    int s = 0;
#pragma unroll
    for (int k = 0; k < 4; ++k) {
        v[k] = (tb + k < n) ? cnt[tb + k] : 0;
        s += v[k];
    }
    sc[tid] = s;
    __syncthreads();
#pragma unroll
    for (int off = 1; off < 256; off <<= 1) {
        int t = (tid >= off) ? sc[tid - off] : 0;
        __syncthreads();
        sc[tid] += t;
        __syncthreads();
    }
    int ex = part[blockIdx.x] + (tid ? sc[tid - 1] : 0);
#pragma unroll
    for (int k = 0; k < 4; ++k) {
        if (tb + k < n) {
            offs[tb + k] = ex;
            cursor[tb + k] = ex;
            ex += v[k];
        }
    }
}

__global__ __launch_bounds__(256) void fill_kernel(
    const int* __restrict__ src, const int* __restrict__ dst,
    int* __restrict__ cursor, int* __restrict__ col, int ne)
{
    int stride = gridDim.x * blockDim.x;
    for (int e = blockIdx.x * blockDim.x + threadIdx.x; e < ne; e += stride) {
        int p = atomicAdd(&cursor[dst[e]], 1);
        col[p] = src[e];
    }
}

// ---------------------------------------------------------------------------
// CSR mean-aggregation (bf16 in/out): one wave per destination node.
// The wave's two 32-lane halves process different edges; each lane covers
// 4 columns (uint2 = 4 bf16, 8 B). Halves are combined with shfl_xor(32).
// ---------------------------------------------------------------------------
__global__ __launch_bounds__(256) void agg_mean_bf16(
    const int* __restrict__ offs, const int* __restrict__ col,
    const unsigned short* __restrict__ X, unsigned short* __restrict__ M, int n)
{
    int wid = (blockIdx.x * blockDim.x + threadIdx.x) >> 6;
    int lane = threadIdx.x & 63;
    if (wid >= n) return;
    const int half = lane >> 5;
    const int l32 = lane & 31;

    const int start = offs[wid];
    const int end = offs[wid + 1];
    float a0 = 0.f, a1 = 0.f, a2 = 0.f, a3 = 0.f;
    int e = start;
    for (; e + 1 < end; e += 2) {
        int s0 = col[e + half];
        uint2 v = *reinterpret_cast<const uint2*>(X + (size_t)s0 * HID + l32 * 4);
        a0 += bf2f((unsigned short)(v.x & 0xffffu));
        a1 += bf2f((unsigned short)(v.x >> 16));
        a2 += bf2f((unsigned short)(v.y & 0xffffu));
        a3 += bf2f((unsigned short)(v.y >> 16));
    }
    if (e < end && half == 0) {
        int s0 = col[e];
        uint2 v = *reinterpret_cast<const uint2*>(X + (size_t)s0 * HID + l32 * 4);
        a0 += bf2f((unsigned short)(v.x & 0xffffu));
        a1 += bf2f((unsigned short)(v.x >> 16));
        a2 += bf2f((unsigned short)(v.y & 0xffffu));
        a3 += bf2f((unsigned short)(v.y >> 16));
    }
    a0 += __shfl_xor(a0, 32, 64);
    a1 += __shfl_xor(a1, 32, 64);
    a2 += __shfl_xor(a2, 32, 64);
    a3 += __shfl_xor(a3, 32, 64);

    if (half == 0) {
        float inv = 1.0f / (float)max(end - start, 1);
        uint2 o;
        o.x = (unsigned int)f2bf(a0 * inv) | ((unsigned int)f2bf(a1 * inv) << 16);
        o.y = (unsigned int)f2bf(a2 * inv) | ((unsigned int)f2bf(a3 * inv) << 16);
        *reinterpret_cast<uint2*>(M + (size_t)wid * HID + l32 * 4) = o;
    }
}

// ---------------------------------------------------------------------------
// Weight prep: Wt[j][k] = bf16( k<128 ? Wl[k][j] : Wr[k-128][j] ), j in [0,CO)
// ---------------------------------------------------------------------------
__global__ __launch_bounds__(256) void prep_w(
    const float* __restrict__ Wl, const float* __restrict__ Wr,
    unsigned short* __restrict__ Wt, int CO)
{
    int idx = blockIdx.x * 256 + threadIdx.x;   // CO*256 total
    int j = idx >> 8;
    int k = idx & 255;
    float v = (k < HID) ? Wl[k * CO + j] : Wr[(k - HID) * CO + j];
    Wt[(size_t)j * 256 + k] = f2bf(v);
}

// ---------------------------------------------------------------------------
// Single-edge-type MFMA SAGE (used for td): out = norm([mean|x]@Wt + bl)
// Block = 4 waves; each wave computes a 16-node x CO tile. K = 256.
// C/D layout: col = lane&15, row = (lane>>4)*4 + reg   [verified m89]
// ---------------------------------------------------------------------------
template <int CO>
__global__ __launch_bounds__(256) void sage_mfma(
    const unsigned short* __restrict__ Mb,
    const unsigned short* __restrict__ Xb,
    const unsigned short* __restrict__ Wt,
    const float* __restrict__ bl,
    float* __restrict__ H, int n)
{
    constexpr int NT = CO / 16;
    const int wave = threadIdx.x >> 6;
    const int lane = threadIdx.x & 63;
    const int r16 = lane & 15;
    const int chunk = lane >> 4;
    const int rowbase = blockIdx.x * 64 + wave * 16;

    const int arow = min(rowbase + r16, n - 1);
    const unsigned short* mrow = Mb + (size_t)arow * HID;
    const unsigned short* xrow = Xb + (size_t)arow * HID;

    bf16x8 a[8];
#pragma unroll
    for (int s = 0; s < 4; ++s)
        a[s] = *reinterpret_cast<const bf16x8*>(mrow + s * 32 + chunk * 8);
#pragma unroll
    for (int s = 0; s < 4; ++s)
        a[4 + s] = *reinterpret_cast<const bf16x8*>(xrow + s * 32 + chunk * 8);

    f32x4 acc[NT];
#pragma unroll
    for (int t = 0; t < NT; ++t) acc[t] = f32x4{0.f, 0.f, 0.f, 0.f};

#pragma unroll
    for (int t = 0; t < NT; ++t) {
        const unsigned short* wr_ = Wt + (size_t)(t * 16 + r16) * 256;
#pragma unroll
        for (int s = 0; s < 8; ++s) {
            bf16x8 b = *reinterpret_cast<const bf16x8*>(wr_ + s * 32 + chunk * 8);
            acc[t] = __builtin_amdgcn_mfma_f32_16x16x32_bf16(a[s], b, acc[t], 0, 0, 0);
        }
    }

    float ss[4] = {0.f, 0.f, 0.f, 0.f};
#pragma unroll
    for (int t = 0; t < NT; ++t) {
        float bias = bl[t * 16 + r16];
#pragma unroll
        for (int r = 0; r < 4; ++r) {
            acc[t][r] += bias;
            ss[r] += acc[t][r] * acc[t][r];
        }
    }
#pragma unroll
    for (int r = 0; r < 4; ++r) {
#pragma unroll
        for (int m = 1; m < 16; m <<= 1)
            ss[r] += __shfl_xor(ss[r], m, 64);
    }

#pragma unroll
    for (int r = 0; r < 4; ++r) {
        int node = rowbase + chunk * 4 + r;
        if (node < n) {
            float inv = 1.0f / fmaxf(sqrtf(ss[r]), 1e-12f);
#pragma unroll
            for (int t = 0; t < NT; ++t)
                H[(size_t)node * CO + t * 16 + r16] = acc[t][r] * inv;
        }
    }
}

// ---------------------------------------------------------------------------
// Fused dual-edge-type SAGE (dd + rd -> drug destinations):
//   H = norm([mA|x]@WtA + blA) + norm([mB|x]@WtB + blB), single write.
// ---------------------------------------------------------------------------
template <int CO>
__global__ __launch_bounds__(256) void sage2_mfma(
    const unsigned short* __restrict__ MbA,
    const unsigned short* __restrict__ MbB,
    const unsigned short* __restrict__ Xb,
    const unsigned short* __restrict__ WtA,
    const unsigned short* __restrict__ WtB,
    const float* __restrict__ blA, const float* __restrict__ blB,
    float* __restrict__ H, int n)
{
    constexpr int NT = CO / 16;
    const int wave = threadIdx.x >> 6;
    const int lane = threadIdx.x & 63;
    const int r16 = lane & 15;
    const int chunk = lane >> 4;
    const int rowbase = blockIdx.x * 64 + wave * 16;

    const int arow = min(rowbase + r16, n - 1);
    const unsigned short* marow = MbA + (size_t)arow * HID;
    const unsigned short* mbrow = MbB + (size_t)arow * HID;
    const unsigned short* xrow  = Xb  + (size_t)arow * HID;

    bf16x8 aA[4], aB[4], ax[4];
#pragma unroll
    for (int s = 0; s < 4; ++s) {
        aA[s] = *reinterpret_cast<const bf16x8*>(marow + s * 32 + chunk * 8);
        aB[s] = *reinterpret_cast<const bf16x8*>(mbrow + s * 32 + chunk * 8);
        ax[s] = *reinterpret_cast<const bf16x8*>(xrow  + s * 32 + chunk * 8);
    }

    f32x4 accA[NT], accB[NT];
#pragma unroll
    for (int t = 0; t < NT; ++t) {
        accA[t] = f32x4{0.f, 0.f, 0.f, 0.f};
        accB[t] = f32x4{0.f, 0.f, 0.f, 0.f};
    }

#pragma unroll
    for (int t = 0; t < NT; ++t) {
        const unsigned short* wA = WtA + (size_t)(t * 16 + r16) * 256;
        const unsigned short* wB = WtB + (size_t)(t * 16 + r16) * 256;
#pragma unroll
        for (int s = 0; s < 4; ++s) {
            bf16x8 b0 = *reinterpret_cast<const bf16x8*>(wA + s * 32 + chunk * 8);
            accA[t] = __builtin_amdgcn_mfma_f32_16x16x32_bf16(aA[s], b0, accA[t], 0, 0, 0);
            bf16x8 b1 = *reinterpret_cast<const bf16x8*>(wA + HID + s * 32 + chunk * 8);
            accA[t] = __builtin_amdgcn_mfma_f32_16x16x32_bf16(ax[s], b1, accA[t], 0, 0, 0);
            bf16x8 b2 = *reinterpret_cast<const bf16x8*>(wB + s * 32 + chunk * 8);
            accB[t] = __builtin_amdgcn_mfma_f32_16x16x32_bf16(aB[s], b2, accB[t], 0, 0, 0);
            bf16x8 b3 = *reinterpret_cast<const bf16x8*>(wB + HID + s * 32 + chunk * 8);
            accB[t] = __builtin_amdgcn_mfma_f32_16x16x32_bf16(ax[s], b3, accB[t], 0, 0, 0);
        }
    }

    float ssA[4] = {0.f, 0.f, 0.f, 0.f};
    float ssB[4] = {0.f, 0.f, 0.f, 0.f};
#pragma unroll
    for (int t = 0; t < NT; ++t) {
        float biasA = blA[t * 16 + r16];
        float biasB = blB[t * 16 + r16];
#pragma unroll
        for (int r = 0; r < 4; ++r) {
            accA[t][r] += biasA;
            ssA[r] += accA[t][r] * accA[t][r];
            accB[t][r] += biasB;
            ssB[r] += accB[t][r] * accB[t][r];
        }
    }
#pragma unroll
    for (int r = 0; r < 4; ++r) {
#pragma unroll
        for (int m = 1; m < 16; m <<= 1) {
            ssA[r] += __shfl_xor(ssA[r], m, 64);
            ssB[r] += __shfl_xor(ssB[r], m, 64);
        }
    }

#pragma unroll
    for (int r = 0; r < 4; ++r) {
        int node = rowbase + chunk * 4 + r;
        if (node < n) {
            float invA = 1.0f / fmaxf(sqrtf(ssA[r]), 1e-12f);
            float invB = 1.0f / fmaxf(sqrtf(ssB[r]), 1e-12f);
#pragma unroll
            for (int t = 0; t < NT; ++t)
                H[(size_t)node * CO + t * 16 + r16] =
                    accA[t][r] * invA + accB[t][r] * invB;
        }
    }
}

// ---------------------------------------------------------------------------
// LayerNorm (+optional ReLU), one wave per row; fp32 in; bf16 or fp32 out.
// ---------------------------------------------------------------------------
template <int D, bool RELU, bool OUTBF>
__global__ __launch_bounds__(256) void ln_kernel(
    const float* __restrict__ X, const float* __restrict__ gg,
    const float* __restrict__ bb, void* __restrict__ outp, int n)
{
    constexpr int VPL = D / 64;
    int wid = (blockIdx.x * blockDim.x + threadIdx.x) >> 6;
    int lane = threadIdx.x & 63;
    if (wid >= n) return;

    float v[VPL], gv[VPL], bv[VPL];
    const float* xp = X + (size_t)wid * D + lane * VPL;
#pragma unroll
    for (int k = 0; k < VPL; ++k) {
        v[k] = xp[k];
        gv[k] = gg[lane * VPL + k];
        bv[k] = bb[lane * VPL + k];
    }
    float s = 0.f;
#pragma unroll
    for (int k = 0; k < VPL; ++k) s += v[k];
#pragma unroll
    for (int off = 32; off > 0; off >>= 1) s += __shfl_xor(s, off, 64);
    float m = s / D;
    float ss = 0.f;
#pragma unroll
    for (int k = 0; k < VPL; ++k) { float d = v[k] - m; ss += d * d; }
#pragma unroll
    for (int off = 32; off > 0; off >>= 1) ss += __shfl_xor(ss, off, 64);
    float rstd = rsqrtf(ss / D + 1e-5f);

    float y[VPL];
#pragma unroll
    for (int k = 0; k < VPL; ++k) {
        y[k] = gv[k] * (v[k] - m) * rstd + bv[k];
        if (RELU) y[k] = fmaxf(y[k], 0.f);
    }
    if (OUTBF) {
        unsigned short* op = (unsigned short*)outp + (size_t)wid * D + lane * VPL;
#pragma unroll
        for (int k = 0; k < VPL; ++k) op[k] = f2bf(y[k]);
    } else {
        float* op = (float*)outp + (size_t)wid * D + lane * VPL;
#pragma unroll
        for (int k = 0; k < VPL; ++k) op[k] = y[k];
    }
}

// ---------------------------------------------------------------------------
extern "C" void kernel_launch(void* const* d_in, const int* in_sizes, int n_in,
                              void* d_out, int out_size, void* d_ws, size_t ws_size,
                              hipStream_t stream)
{
    const int*   x_drug   = (const int*)d_in[0];
    const int*   x_dis    = (const int*)d_in[1];
    const float* emb_drug = (const float*)d_in[2];
    const float* emb_dis  = (const float*)d_in[3];
    const int*   src_dd   = (const int*)d_in[4];
    const int*   dst_dd   = (const int*)d_in[5];
    const int*   src_td   = (const int*)d_in[6];
    const int*   dst_td   = (const int*)d_in[7];
    const int*   src_rd   = (const int*)d_in[8];
    const int*   dst_rd   = (const int*)d_in[9];
    const float* Wl0_dd = (const float*)d_in[10];
    const float* bl0_dd = (const float*)d_in[11];
    const float* Wr0_dd = (const float*)d_in[12];
    const float* Wl0_td = (const float*)d_in[13];
    const float* bl0_td = (const float*)d_in[14];
    const float* Wr0_td = (const float*)d_in[15];
    const float* Wl0_rd = (const float*)d_in[16];
    const float* bl0_rd = (const float*)d_in[17];
    const float* Wr0_rd = (const float*)d_in[18];
    const float* Wl1_dd = (const float*)d_in[19];
    const float* bl1_dd = (const float*)d_in[20];
    const float* Wr1_dd = (const float*)d_in[21];
    const float* Wl1_td = (const float*)d_in[22];
    const float* bl1_td = (const float*)d_in[23];
    const float* Wr1_td = (const float*)d_in[24];
    const float* Wl1_rd = (const float*)d_in[25];
    const float* bl1_rd = (const float*)d_in[26];
    const float* Wr1_rd = (const float*)d_in[27];
    const float* g0_drug = (const float*)d_in[28];
    const float* b0_drug = (const float*)d_in[29];
    const float* g0_dis  = (const float*)d_in[30];
    const float* b0_dis  = (const float*)d_in[31];
    const float* g1_drug = (const float*)d_in[32];
    const float* b1_drug = (const float*)d_in[33];
    const float* g1_dis  = (const float*)d_in[34];
    const float* b1_dis  = (const float*)d_in[35];

    // ---------------- workspace layout ----------------
    char* wp = (char*)d_ws;
    auto alloc = [&](size_t bytes) { char* p = wp; wp += (bytes + 255) & ~size_t(255); return p; };

    unsigned short* hd0  = (unsigned short*)alloc((size_t)ND * HID * 2);
    unsigned short* hz0  = (unsigned short*)alloc((size_t)NZ * HID * 2);
    unsigned short* hd1b = (unsigned short*)alloc((size_t)ND * HID * 2);
    unsigned short* hz1b = (unsigned short*)alloc((size_t)NZ * HID * 2);
    unsigned short* meanA= (unsigned short*)alloc((size_t)ND * HID * 2);
    unsigned short* meanB= (unsigned short*)alloc((size_t)ND * HID * 2);
    float* hd1f = (float*)alloc((size_t)ND * HID * 4);
    float* hz1f = (float*)alloc((size_t)NZ * HID * 4);
    unsigned short* Wt0_dd = (unsigned short*)alloc((size_t)HID * 256 * 2);
    unsigned short* Wt0_rd = (unsigned short*)alloc((size_t)HID * 256 * 2);
    unsigned short* Wt0_td = (unsigned short*)alloc((size_t)HID * 256 * 2);
    unsigned short* Wt1_dd = (unsigned short*)alloc((size_t)OUTD * 256 * 2);
    unsigned short* Wt1_rd = (unsigned short*)alloc((size_t)OUTD * 256 * 2);
    unsigned short* Wt1_td = (unsigned short*)alloc((size_t)OUTD * 256 * 2);
    int* offs_dd = (int*)alloc((ND + 1) * 4);
    int* offs_rd = (int*)alloc((ND + 1) * 4);
    int* offs_td = (int*)alloc((NZ + 1) * 4);
    int* col_dd  = (int*)alloc((size_t)E * 4);
    int* col_rd  = (int*)alloc((size_t)E * 4);
    int* col_td  = (int*)alloc((size_t)E * 4);
    int* cnt     = (int*)alloc((ND + 1) * 4);
    int* cursor  = (int*)alloc((ND + 1) * 4);
    int* part    = (int*)alloc(64 * 4);

    float* outD = (float*)d_out;
    float* outZ = outD + (size_t)ND * OUTD;

    const int NB_D = ceil_div(ND, SCAN_TILE);   // 49
    const int NB_Z = ceil_div(NZ, SCAN_TILE);   // 20

    // ---------------- input gathers + weight prep ----------------
    gather_bf16<<<ceil_div(ND * 32, 256), 256, 0, stream>>>(emb_drug, x_drug, hd0, ND);
    gather_bf16<<<ceil_div(NZ * 32, 256), 256, 0, stream>>>(emb_dis, x_dis, hz0, NZ);

    prep_w<<<HID, 256, 0, stream>>>(Wl0_dd, Wr0_dd, Wt0_dd, HID);
    prep_w<<<HID, 256, 0, stream>>>(Wl0_rd, Wr0_rd, Wt0_rd, HID);
    prep_w<<<HID, 256, 0, stream>>>(Wl0_td, Wr0_td, Wt0_td, HID);
    prep_w<<<OUTD, 256, 0, stream>>>(Wl1_dd, Wr1_dd, Wt1_dd, OUTD);
    prep_w<<<OUTD, 256, 0, stream>>>(Wl1_rd, Wr1_rd, Wt1_rd, OUTD);
    prep_w<<<OUTD, 256, 0, stream>>>(Wl1_td, Wr1_td, Wt1_td, OUTD);

    // ---------------- CSR builds (reused by both layers) ----------------
    auto build_csr = [&](const int* src, const int* dst, int* offs, int* col, int n, int nb) {
        hipMemsetAsync(cnt, 0, (n + 1) * sizeof(int), stream);
        hist_kernel<<<1024, 256, 0, stream>>>(dst, cnt, E);
        scan_part<<<nb, 256, 0, stream>>>(cnt, part, n);
        scan_small<<<1, 64, 0, stream>>>(part, offs, nb, n);
        scan_write<<<nb, 256, 0, stream>>>(cnt, part, offs, cursor, n);
        fill_kernel<<<1024, 256, 0, stream>>>(src, dst, cursor, col, E);
    };
    build_csr(src_dd, dst_dd, offs_dd, col_dd, ND, NB_D);
    build_csr(src_rd, dst_rd, offs_rd, col_rd, ND, NB_D);
    build_csr(src_td, dst_td, offs_td, col_td, NZ, NB_Z);

    // ---------------- layer 0 ----------------
    agg_mean_bf16<<<ceil_div(ND * 64, 256), 256, 0, stream>>>(offs_dd, col_dd, hd0, meanA, ND);
    agg_mean_bf16<<<ceil_div(ND * 64, 256), 256, 0, stream>>>(offs_rd, col_rd, hz0, meanB, ND);
    sage2_mfma<HID><<<ceil_div(ND, 64), 256, 0, stream>>>(meanA, meanB, hd0, Wt0_dd, Wt0_rd, bl0_dd, bl0_rd, hd1f, ND);

    agg_mean_bf16<<<ceil_div(NZ * 64, 256), 256, 0, stream>>>(offs_td, col_td, hd0, meanA, NZ);
    sage_mfma<HID><<<ceil_div(NZ, 64), 256, 0, stream>>>(meanA, hz0, Wt0_td, bl0_td, hz1f, NZ);

    ln_kernel<HID, true, true><<<ceil_div(ND, 4), 256, 0, stream>>>(hd1f, g0_drug, b0_drug, hd1b, ND);
    ln_kernel<HID, true, true><<<ceil_div(NZ, 4), 256, 0, stream>>>(hz1f, g0_dis, b0_dis, hz1b, NZ);

    // ---------------- layer 1 ----------------
    agg_mean_bf16<<<ceil_div(ND * 64, 256), 256, 0, stream>>>(offs_dd, col_dd, hd1b, meanA, ND);
    agg_mean_bf16<<<ceil_div(ND * 64, 256), 256, 0, stream>>>(offs_rd, col_rd, hz1b, meanB, ND);
    sage2_mfma<OUTD><<<ceil_div(ND, 64), 256, 0, stream>>>(meanA, meanB, hd1b, Wt1_dd, Wt1_rd, bl1_dd, bl1_rd, outD, ND);

    agg_mean_bf16<<<ceil_div(NZ * 64, 256), 256, 0, stream>>>(offs_td, col_td, hd1b, meanA, NZ);
    sage_mfma<OUTD><<<ceil_div(NZ, 64), 256, 0, stream>>>(meanA, hz1b, Wt1_td, bl1_td, outZ, NZ);

    ln_kernel<OUTD, false, false><<<ceil_div(ND, 4), 256, 0, stream>>>(outD, g1_drug, b1_drug, outD, ND);
    ln_kernel<OUTD, false, false><<<ceil_div(NZ, 4), 256, 0, stream>>>(outZ, g1_dis, b1_dis, outZ, NZ);
}

// Round 6
// 891.785 us; speedup vs baseline: 6.3951x; 1.0429x over previous
//
#include <hip/hip_runtime.h>

// Problem constants (match reference setup_inputs)
constexpr int ND   = 50000;
constexpr int NZ   = 20000;
constexpr int HID  = 128;
constexpr int OUTD = 64;
constexpr int E    = 1000000;

constexpr int SCAN_TILE = 1024;
constexpr int NB_D = (ND + SCAN_TILE - 1) / SCAN_TILE;   // 49
constexpr int NB_Z = (NZ + SCAN_TILE - 1) / SCAN_TILE;   // 20
constexpr int HB   = 1024;   // hist blocks per edge list
constexpr int FB   = 2048;   // fill blocks per edge list

static inline int ceil_div(int a, int b) { return (a + b - 1) / b; }

typedef __bf16 bf16x8 __attribute__((ext_vector_type(8)));
typedef float  f32x4  __attribute__((ext_vector_type(4)));

__device__ __forceinline__ float bf2f(unsigned short b) {
    return __uint_as_float(((unsigned int)b) << 16);
}
__device__ __forceinline__ unsigned short f2bf(float f) {
    unsigned int u = __float_as_uint(f);
    unsigned int r = (u + 0x7fffu + ((u >> 16) & 1u)) >> 16;
    return (unsigned short)r;
}

// ---------------------------------------------------------------------------
// Fused gather: rows [0,ND) from emb_drug[x_drug], rows [ND,ND+NZ) from emb_dis
// ---------------------------------------------------------------------------
__global__ __launch_bounds__(256) void gather_all(
    const float* __restrict__ emb_d, const int* __restrict__ idx_d,
    const float* __restrict__ emb_z, const int* __restrict__ idx_z,
    unsigned short* __restrict__ out_d, unsigned short* __restrict__ out_z)
{
    int t = blockIdx.x * blockDim.x + threadIdx.x;
    int row = t >> 5;
    int c = (t & 31) * 4;
    if (row >= ND + NZ) return;
    const float* src;
    unsigned short* dst;
    if (row < ND) {
        src = emb_d + (size_t)idx_d[row] * HID;
        dst = out_d + (size_t)row * HID;
    } else {
        int r2 = row - ND;
        src = emb_z + (size_t)idx_z[r2] * HID;
        dst = out_z + (size_t)r2 * HID;
    }
    float4 v = *reinterpret_cast<const float4*>(src + c);
    ushort4 o;
    o.x = f2bf(v.x); o.y = f2bf(v.y); o.z = f2bf(v.z); o.w = f2bf(v.w);
    *reinterpret_cast<ushort4*>(dst + c) = o;
}

// ---------------------------------------------------------------------------
// Fused weight prep: 6 weight pairs -> Wt[j][0:256] = bf16([Wl col j ; Wr col j])
// ---------------------------------------------------------------------------
struct PrepArgs {
    const float* wl[6];
    const float* wr[6];
    unsigned short* wt[6];
    int co[6];
    int boff[7];
};

__global__ __launch_bounds__(256) void prep_all(PrepArgs a)
{
    int sec = 0;
#pragma unroll
    for (int s = 0; s < 6; ++s)
        if ((int)blockIdx.x >= a.boff[s + 1]) sec = s + 1;
    int CO = a.co[sec];
    int idx = (blockIdx.x - a.boff[sec]) * 256 + threadIdx.x;  // CO*256 total
    int j = idx >> 8;
    int k = idx & 255;
    float v = (k < HID) ? a.wl[sec][k * CO + j] : a.wr[sec][(k - HID) * CO + j];
    a.wt[sec][(size_t)j * 256 + k] = f2bf(v);
}

// ---------------------------------------------------------------------------
// Fused histogram over the 3 edge lists
// ---------------------------------------------------------------------------
__global__ __launch_bounds__(256) void hist3(
    const int* __restrict__ d0, const int* __restrict__ d1, const int* __restrict__ d2,
    int* __restrict__ c0, int* __restrict__ c1, int* __restrict__ c2)
{
    int which = blockIdx.x / HB;
    int lb = blockIdx.x % HB;
    const int* dst = (which == 0) ? d0 : (which == 1) ? d1 : d2;
    int* cnt = (which == 0) ? c0 : (which == 1) ? c1 : c2;
    for (int e = lb * 256 + threadIdx.x; e < E; e += HB * 256)
        atomicAdd(&cnt[dst[e]], 1);
}

// ---------------------------------------------------------------------------
// Fused 3-phase scan over the 3 count arrays
// ---------------------------------------------------------------------------
__device__ __forceinline__ void scan_map(int b, int& which, int& tile) {
    if (b < NB_D) { which = 0; tile = b; }
    else if (b < 2 * NB_D) { which = 1; tile = b - NB_D; }
    else { which = 2; tile = b - 2 * NB_D; }
}

__global__ __launch_bounds__(256) void scan_part3(
    const int* __restrict__ c0, const int* __restrict__ c1, const int* __restrict__ c2,
    int* __restrict__ part)
{
    __shared__ int red[256];
    int which, tile;
    scan_map(blockIdx.x, which, tile);
    const int* cnt = (which == 0) ? c0 : (which == 1) ? c1 : c2;
    int n = (which == 2) ? NZ : ND;
    int base = tile * SCAN_TILE;
    int s = 0;
    for (int i = threadIdx.x; i < SCAN_TILE; i += 256) {
        int idx = base + i;
        if (idx < n) s += cnt[idx];
    }
    red[threadIdx.x] = s;
    __syncthreads();
#pragma unroll
    for (int off = 128; off > 0; off >>= 1) {
        if (threadIdx.x < off) red[threadIdx.x] += red[threadIdx.x + off];
        __syncthreads();
    }
    if (threadIdx.x == 0) part[which * 64 + tile] = red[0];
}

__global__ __launch_bounds__(64) void scan_small3(
    int* __restrict__ part,
    int* __restrict__ o0, int* __restrict__ o1, int* __restrict__ o2)
{
    int w = blockIdx.x;
    int np = (w == 2) ? NB_Z : NB_D;
    int n = (w == 2) ? NZ : ND;
    int* offs = (w == 0) ? o0 : (w == 1) ? o1 : o2;
    int* pb = part + w * 64;
    int lane = threadIdx.x;
    int orig = (lane < np) ? pb[lane] : 0;
    int v = orig;
#pragma unroll
    for (int off = 1; off < 64; off <<= 1) {
        int t = __shfl_up(v, off, 64);
        if (lane >= off) v += t;
    }
    if (lane < np) pb[lane] = v - orig;   // exclusive
    if (lane == 63) offs[n] = v;          // total
}

__global__ __launch_bounds__(256) void scan_write3(
    const int* __restrict__ c0, const int* __restrict__ c1, const int* __restrict__ c2,
    const int* __restrict__ part,
    int* __restrict__ o0, int* __restrict__ o1, int* __restrict__ o2,
    int* __restrict__ u0, int* __restrict__ u1, int* __restrict__ u2)
{
    __shared__ int sc[256];
    int which, tile;
    scan_map(blockIdx.x, which, tile);
    const int* cnt = (which == 0) ? c0 : (which == 1) ? c1 : c2;
    int* offs = (which == 0) ? o0 : (which == 1) ? o1 : o2;
    int* cur  = (which == 0) ? u0 : (which == 1) ? u1 : u2;
    int n = (which == 2) ? NZ : ND;

    const int tid = threadIdx.x;
    const int tb = tile * SCAN_TILE + tid * 4;
    int v[4];
    int s = 0;
#pragma unroll
    for (int k = 0; k < 4; ++k) {
        v[k] = (tb + k < n) ? cnt[tb + k] : 0;
        s += v[k];
    }
    sc[tid] = s;
    __syncthreads();
#pragma unroll
    for (int off = 1; off < 256; off <<= 1) {
        int t = (tid >= off) ? sc[tid - off] : 0;
        __syncthreads();
        sc[tid] += t;
        __syncthreads();
    }
    int ex = part[which * 64 + tile] + (tid ? sc[tid - 1] : 0);
#pragma unroll
    for (int k = 0; k < 4; ++k) {
        if (tb + k < n) {
            offs[tb + k] = ex;
            cur[tb + k] = ex;
            ex += v[k];
        }
    }
}

// ---------------------------------------------------------------------------
// Fused CSR fill over the 3 edge lists
// ---------------------------------------------------------------------------
__global__ __launch_bounds__(256) void fill3(
    const int* __restrict__ s0, const int* __restrict__ d0,
    const int* __restrict__ s1, const int* __restrict__ d1,
    const int* __restrict__ s2, const int* __restrict__ d2,
    int* __restrict__ u0, int* __restrict__ u1, int* __restrict__ u2,
    int* __restrict__ l0, int* __restrict__ l1, int* __restrict__ l2)
{
    int which = blockIdx.x / FB;
    int lb = blockIdx.x % FB;
    const int* src = (which == 0) ? s0 : (which == 1) ? s1 : s2;
    const int* dst = (which == 0) ? d0 : (which == 1) ? d1 : d2;
    int* cur = (which == 0) ? u0 : (which == 1) ? u1 : u2;
    int* col = (which == 0) ? l0 : (which == 1) ? l1 : l2;
    for (int e = lb * 256 + threadIdx.x; e < E; e += FB * 256) {
        int p = atomicAdd(&cur[dst[e]], 1);
        col[p] = src[e];
    }
}

// ---------------------------------------------------------------------------
// Fused CSR mean-aggregation over 3 (offs,col,X,M) sets; one wave per node.
// Wave halves process alternate edges; lane covers 4 cols (uint2 = 4 bf16).
// ---------------------------------------------------------------------------
__global__ __launch_bounds__(256) void agg3(
    const int* __restrict__ o0, const int* __restrict__ c0,
    const unsigned short* __restrict__ X0, unsigned short* __restrict__ M0, int n0,
    const int* __restrict__ o1, const int* __restrict__ c1,
    const unsigned short* __restrict__ X1, unsigned short* __restrict__ M1, int n1,
    const int* __restrict__ o2, const int* __restrict__ c2,
    const unsigned short* __restrict__ X2, unsigned short* __restrict__ M2, int n2)
{
    int wid = (blockIdx.x * blockDim.x + threadIdx.x) >> 6;
    const int lane = threadIdx.x & 63;
    const int half = lane >> 5;
    const int l32 = lane & 31;

    const int* offs; const int* col;
    const unsigned short* X; unsigned short* M;
    if (wid < n0) { offs = o0; col = c0; X = X0; M = M0; }
    else if (wid < n0 + n1) { wid -= n0; offs = o1; col = c1; X = X1; M = M1; }
    else { wid -= n0 + n1; if (wid >= n2) return; offs = o2; col = c2; X = X2; M = M2; }

    const int start = offs[wid];
    const int end = offs[wid + 1];
    float a0 = 0.f, a1 = 0.f, a2 = 0.f, a3 = 0.f;
    int e = start;
    for (; e + 1 < end; e += 2) {
        int s0 = col[e + half];
        uint2 v = *reinterpret_cast<const uint2*>(X + (size_t)s0 * HID + l32 * 4);
        a0 += bf2f((unsigned short)(v.x & 0xffffu));
        a1 += bf2f((unsigned short)(v.x >> 16));
        a2 += bf2f((unsigned short)(v.y & 0xffffu));
        a3 += bf2f((unsigned short)(v.y >> 16));
    }
    if (e < end && half == 0) {
        int s0 = col[e];
        uint2 v = *reinterpret_cast<const uint2*>(X + (size_t)s0 * HID + l32 * 4);
        a0 += bf2f((unsigned short)(v.x & 0xffffu));
        a1 += bf2f((unsigned short)(v.x >> 16));
        a2 += bf2f((unsigned short)(v.y & 0xffffu));
        a3 += bf2f((unsigned short)(v.y >> 16));
    }
    a0 += __shfl_xor(a0, 32, 64);
    a1 += __shfl_xor(a1, 32, 64);
    a2 += __shfl_xor(a2, 32, 64);
    a3 += __shfl_xor(a3, 32, 64);

    if (half == 0) {
        float inv = 1.0f / (float)max(end - start, 1);
        uint2 o;
        o.x = (unsigned int)f2bf(a0 * inv) | ((unsigned int)f2bf(a1 * inv) << 16);
        o.y = (unsigned int)f2bf(a2 * inv) | ((unsigned int)f2bf(a3 * inv) << 16);
        *reinterpret_cast<uint2*>(M + (size_t)wid * HID + l32 * 4) = o;
    }
}

// ---------------------------------------------------------------------------
// Single-edge-type MFMA SAGE (td): out = norm([mean|x]@Wt + bl), fp32 write.
// C/D layout: col = lane&15, row = (lane>>4)*4 + reg   [verified m89]
// ---------------------------------------------------------------------------
template <int CO>
__global__ __launch_bounds__(256) void sage_mfma(
    const unsigned short* __restrict__ Mb,
    const unsigned short* __restrict__ Xb,
    const unsigned short* __restrict__ Wt,
    const float* __restrict__ bl,
    float* __restrict__ H, int n)
{
    constexpr int NT = CO / 16;
    const int wave = threadIdx.x >> 6;
    const int lane = threadIdx.x & 63;
    const int r16 = lane & 15;
    const int chunk = lane >> 4;
    const int rowbase = blockIdx.x * 64 + wave * 16;
    if (rowbase >= n) return;

    const int arow = min(rowbase + r16, n - 1);
    const unsigned short* mrow = Mb + (size_t)arow * HID;
    const unsigned short* xrow = Xb + (size_t)arow * HID;

    bf16x8 a[8];
#pragma unroll
    for (int s = 0; s < 4; ++s) {
        a[s]     = *reinterpret_cast<const bf16x8*>(mrow + s * 32 + chunk * 8);
        a[4 + s] = *reinterpret_cast<const bf16x8*>(xrow + s * 32 + chunk * 8);
    }

    f32x4 acc[NT];
#pragma unroll
    for (int t = 0; t < NT; ++t) acc[t] = f32x4{0.f, 0.f, 0.f, 0.f};

#pragma unroll
    for (int t = 0; t < NT; ++t) {
        const unsigned short* wr_ = Wt + (size_t)(t * 16 + r16) * 256;
#pragma unroll
        for (int s = 0; s < 8; ++s) {
            bf16x8 b = *reinterpret_cast<const bf16x8*>(wr_ + s * 32 + chunk * 8);
            acc[t] = __builtin_amdgcn_mfma_f32_16x16x32_bf16(a[s], b, acc[t], 0, 0, 0);
        }
    }

    float ss[4] = {0.f, 0.f, 0.f, 0.f};
#pragma unroll
    for (int t = 0; t < NT; ++t) {
        float bias = bl[t * 16 + r16];
#pragma unroll
        for (int r = 0; r < 4; ++r) {
            acc[t][r] += bias;
            ss[r] += acc[t][r] * acc[t][r];
        }
    }
#pragma unroll
    for (int r = 0; r < 4; ++r)
#pragma unroll
        for (int m = 1; m < 16; m <<= 1)
            ss[r] += __shfl_xor(ss[r], m, 64);

#pragma unroll
    for (int r = 0; r < 4; ++r) {
        int node = rowbase + chunk * 4 + r;
        if (node < n) {
            float inv = 1.0f / fmaxf(sqrtf(ss[r]), 1e-12f);
#pragma unroll
            for (int t = 0; t < NT; ++t)
                H[(size_t)node * CO + t * 16 + r16] = acc[t][r] * inv;
        }
    }
}

// ---------------------------------------------------------------------------
// Dual-edge-type SAGE (dd + rd): H = norm(A-path) + norm(B-path), fp32 write.
// ---------------------------------------------------------------------------
template <int CO>
__global__ __launch_bounds__(256) void sage2_mfma(
    const unsigned short* __restrict__ MbA,
    const unsigned short* __restrict__ MbB,
    const unsigned short* __restrict__ Xb,
    const unsigned short* __restrict__ WtA,
    const unsigned short* __restrict__ WtB,
    const float* __restrict__ blA, const float* __restrict__ blB,
    float* __restrict__ H, int n)
{
    constexpr int NT = CO / 16;
    const int wave = threadIdx.x >> 6;
    const int lane = threadIdx.x & 63;
    const int r16 = lane & 15;
    const int chunk = lane >> 4;
    const int rowbase = blockIdx.x * 64 + wave * 16;
    if (rowbase >= n) return;

    const int arow = min(rowbase + r16, n - 1);
    const unsigned short* marow = MbA + (size_t)arow * HID;
    const unsigned short* mbrow = MbB + (size_t)arow * HID;
    const unsigned short* xrow  = Xb  + (size_t)arow * HID;

    bf16x8 aA[4], aB[4], ax[4];
#pragma unroll
    for (int s = 0; s < 4; ++s) {
        aA[s] = *reinterpret_cast<const bf16x8*>(marow + s * 32 + chunk * 8);
        aB[s] = *reinterpret_cast<const bf16x8*>(mbrow + s * 32 + chunk * 8);
        ax[s] = *reinterpret_cast<const bf16x8*>(xrow  + s * 32 + chunk * 8);
    }

    f32x4 accA[NT], accB[NT];
#pragma unroll
    for (int t = 0; t < NT; ++t) {
        accA[t] = f32x4{0.f, 0.f, 0.f, 0.f};
        accB[t] = f32x4{0.f, 0.f, 0.f, 0.f};
    }

#pragma unroll
    for (int t = 0; t < NT; ++t) {
        const unsigned short* wA = WtA + (size_t)(t * 16 + r16) * 256;
        const unsigned short* wB = WtB + (size_t)(t * 16 + r16) * 256;
#pragma unroll
        for (int s = 0; s < 4; ++s) {
            bf16x8 b0 = *reinterpret_cast<const bf16x8*>(wA + s * 32 + chunk * 8);
            accA[t] = __builtin_amdgcn_mfma_f32_16x16x32_bf16(aA[s], b0, accA[t], 0, 0, 0);
            bf16x8 b1 = *reinterpret_cast<const bf16x8*>(wA + HID + s * 32 + chunk * 8);
            accA[t] = __builtin_amdgcn_mfma_f32_16x16x32_bf16(ax[s], b1, accA[t], 0, 0, 0);
            bf16x8 b2 = *reinterpret_cast<const bf16x8*>(wB + s * 32 + chunk * 8);
            accB[t] = __builtin_amdgcn_mfma_f32_16x16x32_bf16(aB[s], b2, accB[t], 0, 0, 0);
            bf16x8 b3 = *reinterpret_cast<const bf16x8*>(wB + HID + s * 32 + chunk * 8);
            accB[t] = __builtin_amdgcn_mfma_f32_16x16x32_bf16(ax[s], b3, accB[t], 0, 0, 0);
        }
    }

    float ssA[4] = {0.f, 0.f, 0.f, 0.f};
    float ssB[4] = {0.f, 0.f, 0.f, 0.f};
#pragma unroll
    for (int t = 0; t < NT; ++t) {
        float biasA = blA[t * 16 + r16];
        float biasB = blB[t * 16 + r16];
#pragma unroll
        for (int r = 0; r < 4; ++r) {
            accA[t][r] += biasA;
            ssA[r] += accA[t][r] * accA[t][r];
            accB[t][r] += biasB;
            ssB[r] += accB[t][r] * accB[t][r];
        }
    }
#pragma unroll
    for (int r = 0; r < 4; ++r)
#pragma unroll
        for (int m = 1; m < 16; m <<= 1) {
            ssA[r] += __shfl_xor(ssA[r], m, 64);
            ssB[r] += __shfl_xor(ssB[r], m, 64);
        }

#pragma unroll
    for (int r = 0; r < 4; ++r) {
        int node = rowbase + chunk * 4 + r;
        if (node < n) {
            float invA = 1.0f / fmaxf(sqrtf(ssA[r]), 1e-12f);
            float invB = 1.0f / fmaxf(sqrtf(ssB[r]), 1e-12f);
#pragma unroll
            for (int t = 0; t < NT; ++t)
                H[(size_t)node * CO + t * 16 + r16] =
                    accA[t][r] * invA + accB[t][r] * invB;
        }
    }
}

// ---------------------------------------------------------------------------
// LayerNorm (+optional ReLU), one wave per row; fp32 in; bf16 or fp32 out.
// (round-4 exact numerics: two-pass variance, 64-lane reduction)
// ---------------------------------------------------------------------------
template <int D, bool RELU, bool OUTBF>
__global__ __launch_bounds__(256) void ln_kernel(
    const float* __restrict__ X, const float* __restrict__ gg,
    const float* __restrict__ bb, void* __restrict__ outp, int n)
{
    constexpr int VPL = D / 64;
    int wid = (blockIdx.x * blockDim.x + threadIdx.x) >> 6;
    int lane = threadIdx.x & 63;
    if (wid >= n) return;

    float v[VPL], gv[VPL], bv[VPL];
    const float* xp = X + (size_t)wid * D + lane * VPL;
#pragma unroll
    for (int k = 0; k < VPL; ++k) {
        v[k] = xp[k];
        gv[k] = gg[lane * VPL + k];
        bv[k] = bb[lane * VPL + k];
    }
    float s = 0.f;
#pragma unroll
    for (int k = 0; k < VPL; ++k) s += v[k];
#pragma unroll
    for (int off = 32; off > 0; off >>= 1) s += __shfl_xor(s, off, 64);
    float m = s / D;
    float ss = 0.f;
#pragma unroll
    for (int k = 0; k < VPL; ++k) { float d = v[k] - m; ss += d * d; }
#pragma unroll
    for (int off = 32; off > 0; off >>= 1) ss += __shfl_xor(ss, off, 64);
    float rstd = rsqrtf(ss / D + 1e-5f);

    float y[VPL];
#pragma unroll
    for (int k = 0; k < VPL; ++k) {
        y[k] = gv[k] * (v[k] - m) * rstd + bv[k];
        if (RELU) y[k] = fmaxf(y[k], 0.f);
    }
    if (OUTBF) {
        unsigned short* op = (unsigned short*)outp + (size_t)wid * D + lane * VPL;
#pragma unroll
        for (int k = 0; k < VPL; ++k) op[k] = f2bf(y[k]);
    } else {
        float* op = (float*)outp + (size_t)wid * D + lane * VPL;
#pragma unroll
        for (int k = 0; k < VPL; ++k) op[k] = y[k];
    }
}

// ---------------------------------------------------------------------------
extern "C" void kernel_launch(void* const* d_in, const int* in_sizes, int n_in,
                              void* d_out, int out_size, void* d_ws, size_t ws_size,
                              hipStream_t stream)
{
    const int*   x_drug   = (const int*)d_in[0];
    const int*   x_dis    = (const int*)d_in[1];
    const float* emb_drug = (const float*)d_in[2];
    const float* emb_dis  = (const float*)d_in[3];
    const int*   src_dd   = (const int*)d_in[4];
    const int*   dst_dd   = (const int*)d_in[5];
    const int*   src_td   = (const int*)d_in[6];
    const int*   dst_td   = (const int*)d_in[7];
    const int*   src_rd   = (const int*)d_in[8];
    const int*   dst_rd   = (const int*)d_in[9];
    const float* Wl0_dd = (const float*)d_in[10];
    const float* bl0_dd = (const float*)d_in[11];
    const float* Wr0_dd = (const float*)d_in[12];
    const float* Wl0_td = (const float*)d_in[13];
    const float* bl0_td = (const float*)d_in[14];
    const float* Wr0_td = (const float*)d_in[15];
    const float* Wl0_rd = (const float*)d_in[16];
    const float* bl0_rd = (const float*)d_in[17];
    const float* Wr0_rd = (const float*)d_in[18];
    const float* Wl1_dd = (const float*)d_in[19];
    const float* bl1_dd = (const float*)d_in[20];
    const float* Wr1_dd = (const float*)d_in[21];
    const float* Wl1_td = (const float*)d_in[22];
    const float* bl1_td = (const float*)d_in[23];
    const float* Wr1_td = (const float*)d_in[24];
    const float* Wl1_rd = (const float*)d_in[25];
    const float* bl1_rd = (const float*)d_in[26];
    const float* Wr1_rd = (const float*)d_in[27];
    const float* g0_drug = (const float*)d_in[28];
    const float* b0_drug = (const float*)d_in[29];
    const float* g0_dis  = (const float*)d_in[30];
    const float* b0_dis  = (const float*)d_in[31];
    const float* g1_drug = (const float*)d_in[32];
    const float* b1_drug = (const float*)d_in[33];
    const float* g1_dis  = (const float*)d_in[34];
    const float* b1_dis  = (const float*)d_in[35];

    // ---------------- workspace layout ----------------
    char* wp = (char*)d_ws;
    auto alloc = [&](size_t bytes) { char* p = wp; wp += (bytes + 255) & ~size_t(255); return p; };

    unsigned short* hd0  = (unsigned short*)alloc((size_t)ND * HID * 2);
    unsigned short* hz0  = (unsigned short*)alloc((size_t)NZ * HID * 2);
    unsigned short* hd1b = (unsigned short*)alloc((size_t)ND * HID * 2);
    unsigned short* hz1b = (unsigned short*)alloc((size_t)NZ * HID * 2);
    unsigned short* meanA= (unsigned short*)alloc((size_t)ND * HID * 2);
    unsigned short* meanB= (unsigned short*)alloc((size_t)ND * HID * 2);
    unsigned short* meanC= (unsigned short*)alloc((size_t)NZ * HID * 2);
    float* hd1f = (float*)alloc((size_t)ND * HID * 4);
    float* hz1f = (float*)alloc((size_t)NZ * HID * 4);
    unsigned short* Wt0_dd = (unsigned short*)alloc((size_t)HID * 256 * 2);
    unsigned short* Wt0_rd = (unsigned short*)alloc((size_t)HID * 256 * 2);
    unsigned short* Wt0_td = (unsigned short*)alloc((size_t)HID * 256 * 2);
    unsigned short* Wt1_dd = (unsigned short*)alloc((size_t)OUTD * 256 * 2);
    unsigned short* Wt1_rd = (unsigned short*)alloc((size_t)OUTD * 256 * 2);
    unsigned short* Wt1_td = (unsigned short*)alloc((size_t)OUTD * 256 * 2);
    int* offs_dd = (int*)alloc((ND + 1) * 4);
    int* offs_rd = (int*)alloc((ND + 1) * 4);
    int* offs_td = (int*)alloc((NZ + 1) * 4);
    int* col_dd  = (int*)alloc((size_t)E * 4);
    int* col_rd  = (int*)alloc((size_t)E * 4);
    int* col_td  = (int*)alloc((size_t)E * 4);
    // contiguous count region (one memset covers all three)
    int* cnt_dd  = (int*)alloc(((size_t)(ND + 1) + (ND + 1) + (NZ + 1)) * 4);
    int* cnt_rd  = cnt_dd + (ND + 1);
    int* cnt_td  = cnt_rd + (ND + 1);
    int* cur_dd  = (int*)alloc((ND + 1) * 4);
    int* cur_rd  = (int*)alloc((ND + 1) * 4);
    int* cur_td  = (int*)alloc((NZ + 1) * 4);
    int* part    = (int*)alloc(3 * 64 * 4);

    float* outD = (float*)d_out;
    float* outZ = outD + (size_t)ND * OUTD;

    // ---------------- independent prep ----------------
    hipMemsetAsync(cnt_dd, 0, ((size_t)(ND + 1) + (ND + 1) + (NZ + 1)) * 4, stream);

    gather_all<<<ceil_div((ND + NZ) * 32, 256), 256, 0, stream>>>(
        emb_drug, x_drug, emb_dis, x_dis, hd0, hz0);

    PrepArgs pa;
    pa.wl[0] = Wl0_dd; pa.wr[0] = Wr0_dd; pa.wt[0] = Wt0_dd; pa.co[0] = HID;
    pa.wl[1] = Wl0_rd; pa.wr[1] = Wr0_rd; pa.wt[1] = Wt0_rd; pa.co[1] = HID;
    pa.wl[2] = Wl0_td; pa.wr[2] = Wr0_td; pa.wt[2] = Wt0_td; pa.co[2] = HID;
    pa.wl[3] = Wl1_dd; pa.wr[3] = Wr1_dd; pa.wt[3] = Wt1_dd; pa.co[3] = OUTD;
    pa.wl[4] = Wl1_rd; pa.wr[4] = Wr1_rd; pa.wt[4] = Wt1_rd; pa.co[4] = OUTD;
    pa.wl[5] = Wl1_td; pa.wr[5] = Wr1_td; pa.wt[5] = Wt1_td; pa.co[5] = OUTD;
    pa.boff[0] = 0;
    for (int s = 0; s < 6; ++s) pa.boff[s + 1] = pa.boff[s] + pa.co[s];
    prep_all<<<pa.boff[6], 256, 0, stream>>>(pa);

    // ---------------- CSR build (all 3 lists fused per phase) ----------------
    hist3<<<3 * HB, 256, 0, stream>>>(dst_dd, dst_rd, dst_td, cnt_dd, cnt_rd, cnt_td);
    scan_part3<<<2 * NB_D + NB_Z, 256, 0, stream>>>(cnt_dd, cnt_rd, cnt_td, part);
    scan_small3<<<3, 64, 0, stream>>>(part, offs_dd, offs_rd, offs_td);
    scan_write3<<<2 * NB_D + NB_Z, 256, 0, stream>>>(
        cnt_dd, cnt_rd, cnt_td, part, offs_dd, offs_rd, offs_td, cur_dd, cur_rd, cur_td);
    fill3<<<3 * FB, 256, 0, stream>>>(
        src_dd, dst_dd, src_rd, dst_rd, src_td, dst_td,
        cur_dd, cur_rd, cur_td, col_dd, col_rd, col_td);

    // ---------------- layer 0 ----------------
    agg3<<<ceil_div((2 * ND + NZ) * 64, 256), 256, 0, stream>>>(
        offs_dd, col_dd, hd0, meanA, ND,
        offs_rd, col_rd, hz0, meanB, ND,
        offs_td, col_td, hd0, meanC, NZ);
    sage2_mfma<HID><<<ceil_div(ND, 64), 256, 0, stream>>>(
        meanA, meanB, hd0, Wt0_dd, Wt0_rd, bl0_dd, bl0_rd, hd1f, ND);
    sage_mfma<HID><<<ceil_div(NZ, 64), 256, 0, stream>>>(
        meanC, hz0, Wt0_td, bl0_td, hz1f, NZ);

    ln_kernel<HID, true, true><<<ceil_div(ND, 4), 256, 0, stream>>>(hd1f, g0_drug, b0_drug, hd1b, ND);
    ln_kernel<HID, true, true><<<ceil_div(NZ, 4), 256, 0, stream>>>(hz1f, g0_dis, b0_dis, hz1b, NZ);

    // ---------------- layer 1 ----------------
    agg3<<<ceil_div((2 * ND + NZ) * 64, 256), 256, 0, stream>>>(
        offs_dd, col_dd, hd1b, meanA, ND,
        offs_rd, col_rd, hz1b, meanB, ND,
        offs_td, col_td, hd1b, meanC, NZ);
    sage2_mfma<OUTD><<<ceil_div(ND, 64), 256, 0, stream>>>(
        meanA, meanB, hd1b, Wt1_dd, Wt1_rd, bl1_dd, bl1_rd, outD, ND);
    sage_mfma<OUTD><<<ceil_div(NZ, 64), 256, 0, stream>>>(
        meanC, hz1b, Wt1_td, bl1_td, outZ, NZ);

    ln_kernel<OUTD, false, false><<<ceil_div(ND, 4), 256, 0, stream>>>(outD, g1_drug, b1_drug, outD, ND);
    ln_kernel<OUTD, false, false><<<ceil_div(NZ, 4), 256, 0, stream>>>(outZ, g1_dis, b1_dis, outZ, NZ);
}

// Round 7
// 688.465 us; speedup vs baseline: 8.2838x; 1.2953x over previous
//
#include <hip/hip_runtime.h>

// Problem constants (match reference setup_inputs)
constexpr int ND   = 50000;
constexpr int NZ   = 20000;
constexpr int HID  = 128;
constexpr int OUTD = 64;
constexpr int E    = 1000000;

constexpr int SCAN_TILE = 1024;
constexpr int NB_D = (ND + SCAN_TILE - 1) / SCAN_TILE;   // 49
constexpr int NB_Z = (NZ + SCAN_TILE - 1) / SCAN_TILE;   // 20
constexpr int NXCD  = 8;     // XCD count; blockIdx % 8 assumed round-robin -> XCD
constexpr int HISTC = 64;    // chunks per edge list (hist)
constexpr int FILLC = 96;    // chunks per edge list (fill)

static inline int ceil_div(int a, int b) { return (a + b - 1) / b; }

typedef __bf16 bf16x8 __attribute__((ext_vector_type(8)));
typedef float  f32x4  __attribute__((ext_vector_type(4)));

__device__ __forceinline__ float bf2f(unsigned short b) {
    return __uint_as_float(((unsigned int)b) << 16);
}
__device__ __forceinline__ unsigned short f2bf(float f) {
    unsigned int u = __float_as_uint(f);
    unsigned int r = (u + 0x7fffu + ((u >> 16) & 1u)) >> 16;
    return (unsigned short)r;
}

// ---------------------------------------------------------------------------
// Fused gather: rows [0,ND) from emb_drug[x_drug], rows [ND,ND+NZ) from emb_dis
// ---------------------------------------------------------------------------
__global__ __launch_bounds__(256) void gather_all(
    const float* __restrict__ emb_d, const int* __restrict__ idx_d,
    const float* __restrict__ emb_z, const int* __restrict__ idx_z,
    unsigned short* __restrict__ out_d, unsigned short* __restrict__ out_z)
{
    int t = blockIdx.x * blockDim.x + threadIdx.x;
    int row = t >> 5;
    int c = (t & 31) * 4;
    if (row >= ND + NZ) return;
    const float* src;
    unsigned short* dst;
    if (row < ND) {
        src = emb_d + (size_t)idx_d[row] * HID;
        dst = out_d + (size_t)row * HID;
    } else {
        int r2 = row - ND;
        src = emb_z + (size_t)idx_z[r2] * HID;
        dst = out_z + (size_t)r2 * HID;
    }
    float4 v = *reinterpret_cast<const float4*>(src + c);
    ushort4 o;
    o.x = f2bf(v.x); o.y = f2bf(v.y); o.z = f2bf(v.z); o.w = f2bf(v.w);
    *reinterpret_cast<ushort4*>(dst + c) = o;
}

// ---------------------------------------------------------------------------
// Fused weight prep: 6 weight pairs -> Wt[j][0:256] = bf16([Wl col j ; Wr col j])
// ---------------------------------------------------------------------------
struct PrepArgs {
    const float* wl[6];
    const float* wr[6];
    unsigned short* wt[6];
    int co[6];
    int boff[7];
};

__global__ __launch_bounds__(256) void prep_all(PrepArgs a)
{
    int sec = 0;
#pragma unroll
    for (int s = 0; s < 6; ++s)
        if ((int)blockIdx.x >= a.boff[s + 1]) sec = s + 1;
    int CO = a.co[sec];
    int idx = (blockIdx.x - a.boff[sec]) * 256 + threadIdx.x;  // CO*256 total
    int j = idx >> 8;
    int k = idx & 255;
    float v = (k < HID) ? a.wl[sec][k * CO + j] : a.wr[sec][(k - HID) * CO + j];
    a.wt[sec][(size_t)j * 256 + k] = f2bf(v);
}

// ---------------------------------------------------------------------------
// XCD-range-partitioned histogram: blockIdx%8 = destination range (-> XCD),
// so each counter line is touched by only one XCD's L2.
// ---------------------------------------------------------------------------
__global__ __launch_bounds__(256) void hist8(
    const int* __restrict__ d0, const int* __restrict__ d1, const int* __restrict__ d2,
    int* __restrict__ c0, int* __restrict__ c1, int* __restrict__ c2)
{
    const int range = blockIdx.x % NXCD;
    const int t = blockIdx.x / NXCD;
    const int list = t % 3;
    const int chunk = t / 3;                      // [0, HISTC)
    const int* dst = (list == 0) ? d0 : (list == 1) ? d1 : d2;
    int* cnt = (list == 0) ? c0 : (list == 1) ? c1 : c2;
    const int n = (list == 2) ? NZ : ND;
    const int rlo = range * (n / NXCD);
    const int rhi = (range == NXCD - 1) ? n : rlo + n / NXCD;
    const int elo = (int)((long long)chunk * E / HISTC);
    const int ehi = (int)((long long)(chunk + 1) * E / HISTC);
    for (int e = elo + threadIdx.x; e < ehi; e += 256) {
        int d = dst[e];
        if (d >= rlo && d < rhi) atomicAdd(&cnt[d], 1);
    }
}

// ---------------------------------------------------------------------------
// Fused 3-phase scan over the 3 count arrays
// ---------------------------------------------------------------------------
__device__ __forceinline__ void scan_map(int b, int& which, int& tile) {
    if (b < NB_D) { which = 0; tile = b; }
    else if (b < 2 * NB_D) { which = 1; tile = b - NB_D; }
    else { which = 2; tile = b - 2 * NB_D; }
}

__global__ __launch_bounds__(256) void scan_part3(
    const int* __restrict__ c0, const int* __restrict__ c1, const int* __restrict__ c2,
    int* __restrict__ part)
{
    __shared__ int red[256];
    int which, tile;
    scan_map(blockIdx.x, which, tile);
    const int* cnt = (which == 0) ? c0 : (which == 1) ? c1 : c2;
    int n = (which == 2) ? NZ : ND;
    int base = tile * SCAN_TILE;
    int s = 0;
    for (int i = threadIdx.x; i < SCAN_TILE; i += 256) {
        int idx = base + i;
        if (idx < n) s += cnt[idx];
    }
    red[threadIdx.x] = s;
    __syncthreads();
#pragma unroll
    for (int off = 128; off > 0; off >>= 1) {
        if (threadIdx.x < off) red[threadIdx.x] += red[threadIdx.x + off];
        __syncthreads();
    }
    if (threadIdx.x == 0) part[which * 64 + tile] = red[0];
}

__global__ __launch_bounds__(64) void scan_small3(
    int* __restrict__ part,
    int* __restrict__ o0, int* __restrict__ o1, int* __restrict__ o2)
{
    int w = blockIdx.x;
    int np = (w == 2) ? NB_Z : NB_D;
    int n = (w == 2) ? NZ : ND;
    int* offs = (w == 0) ? o0 : (w == 1) ? o1 : o2;
    int* pb = part + w * 64;
    int lane = threadIdx.x;
    int orig = (lane < np) ? pb[lane] : 0;
    int v = orig;
#pragma unroll
    for (int off = 1; off < 64; off <<= 1) {
        int t = __shfl_up(v, off, 64);
        if (lane >= off) v += t;
    }
    if (lane < np) pb[lane] = v - orig;   // exclusive
    if (lane == 63) offs[n] = v;          // total
}

__global__ __launch_bounds__(256) void scan_write3(
    const int* __restrict__ c0, const int* __restrict__ c1, const int* __restrict__ c2,
    const int* __restrict__ part,
    int* __restrict__ o0, int* __restrict__ o1, int* __restrict__ o2,
    int* __restrict__ u0, int* __restrict__ u1, int* __restrict__ u2)
{
    __shared__ int sc[256];
    int which, tile;
    scan_map(blockIdx.x, which, tile);
    const int* cnt = (which == 0) ? c0 : (which == 1) ? c1 : c2;
    int* offs = (which == 0) ? o0 : (which == 1) ? o1 : o2;
    int* cur  = (which == 0) ? u0 : (which == 1) ? u1 : u2;
    int n = (which == 2) ? NZ : ND;

    const int tid = threadIdx.x;
    const int tb = tile * SCAN_TILE + tid * 4;
    int v[4];
    int s = 0;
#pragma unroll
    for (int k = 0; k < 4; ++k) {
        v[k] = (tb + k < n) ? cnt[tb + k] : 0;
        s += v[k];
    }
    sc[tid] = s;
    __syncthreads();
#pragma unroll
    for (int off = 1; off < 256; off <<= 1) {
        int t = (tid >= off) ? sc[tid - off] : 0;
        __syncthreads();
        sc[tid] += t;
        __syncthreads();
    }
    int ex = part[which * 64 + tile] + (tid ? sc[tid - 1] : 0);
#pragma unroll
    for (int k = 0; k < 4; ++k) {
        if (tb + k < n) {
            offs[tb + k] = ex;
            cur[tb + k] = ex;
            ex += v[k];
        }
    }
}

// ---------------------------------------------------------------------------
// XCD-range-partitioned CSR fill: blockIdx%8 = destination range (-> XCD).
// Cursor atomics and col writes for a range stay in one XCD's L2.
// ---------------------------------------------------------------------------
__global__ __launch_bounds__(256) void fill8(
    const int* __restrict__ s0, const int* __restrict__ d0,
    const int* __restrict__ s1, const int* __restrict__ d1,
    const int* __restrict__ s2, const int* __restrict__ d2,
    int* __restrict__ u0, int* __restrict__ u1, int* __restrict__ u2,
    int* __restrict__ l0, int* __restrict__ l1, int* __restrict__ l2)
{
    const int range = blockIdx.x % NXCD;
    const int t = blockIdx.x / NXCD;
    const int list = t % 3;
    const int chunk = t / 3;                      // [0, FILLC)
    const int* src = (list == 0) ? s0 : (list == 1) ? s1 : s2;
    const int* dst = (list == 0) ? d0 : (list == 1) ? d1 : d2;
    int* cur = (list == 0) ? u0 : (list == 1) ? u1 : u2;
    int* col = (list == 0) ? l0 : (list == 1) ? l1 : l2;
    const int n = (list == 2) ? NZ : ND;
    const int rlo = range * (n / NXCD);
    const int rhi = (range == NXCD - 1) ? n : rlo + n / NXCD;
    const int elo = (int)((long long)chunk * E / FILLC);
    const int ehi = (int)((long long)(chunk + 1) * E / FILLC);
    for (int e = elo + threadIdx.x; e < ehi; e += 256) {
        int d = dst[e];
        int s = src[e];                            // unconditional, coalesced
        if (d >= rlo && d < rhi) {
            int p = atomicAdd(&cur[d], 1);
            col[p] = s;
        }
    }
}

// ---------------------------------------------------------------------------
// Fused CSR mean-aggregation over 3 (offs,col,X,M) sets; one wave per node.
// Wave halves process alternate edges; 4-edge unroll (2 per half) for MLP.
// ---------------------------------------------------------------------------
__global__ __launch_bounds__(256) void agg3(
    const int* __restrict__ o0, const int* __restrict__ c0,
    const unsigned short* __restrict__ X0, unsigned short* __restrict__ M0, int n0,
    const int* __restrict__ o1, const int* __restrict__ c1,
    const unsigned short* __restrict__ X1, unsigned short* __restrict__ M1, int n1,
    const int* __restrict__ o2, const int* __restrict__ c2,
    const unsigned short* __restrict__ X2, unsigned short* __restrict__ M2, int n2)
{
    int wid = (blockIdx.x * blockDim.x + threadIdx.x) >> 6;
    const int lane = threadIdx.x & 63;
    const int half = lane >> 5;
    const int l32 = lane & 31;

    const int* offs; const int* col;
    const unsigned short* X; unsigned short* M;
    if (wid < n0) { offs = o0; col = c0; X = X0; M = M0; }
    else if (wid < n0 + n1) { wid -= n0; offs = o1; col = c1; X = X1; M = M1; }
    else { wid -= n0 + n1; if (wid >= n2) return; offs = o2; col = c2; X = X2; M = M2; }

    const int start = offs[wid];
    const int end = offs[wid + 1];
    const unsigned short* Xl = X + l32 * 4;

    float a0 = 0.f, a1 = 0.f, a2 = 0.f, a3 = 0.f;
    float b0 = 0.f, b1 = 0.f, b2 = 0.f, b3 = 0.f;
    int e = start;
    for (; e + 3 < end; e += 4) {
        int sA = col[e + 2 * half];
        int sB = col[e + 2 * half + 1];
        uint2 vA = *reinterpret_cast<const uint2*>(Xl + (size_t)sA * HID);
        uint2 vB = *reinterpret_cast<const uint2*>(Xl + (size_t)sB * HID);
        a0 += bf2f((unsigned short)(vA.x & 0xffffu));
        a1 += bf2f((unsigned short)(vA.x >> 16));
        a2 += bf2f((unsigned short)(vA.y & 0xffffu));
        a3 += bf2f((unsigned short)(vA.y >> 16));
        b0 += bf2f((unsigned short)(vB.x & 0xffffu));
        b1 += bf2f((unsigned short)(vB.x >> 16));
        b2 += bf2f((unsigned short)(vB.y & 0xffffu));
        b3 += bf2f((unsigned short)(vB.y >> 16));
    }
    if (e + 1 < end) {
        int sA = col[e + half];
        uint2 vA = *reinterpret_cast<const uint2*>(Xl + (size_t)sA * HID);
        a0 += bf2f((unsigned short)(vA.x & 0xffffu));
        a1 += bf2f((unsigned short)(vA.x >> 16));
        a2 += bf2f((unsigned short)(vA.y & 0xffffu));
        a3 += bf2f((unsigned short)(vA.y >> 16));
        e += 2;
    }
    if (e < end && half == 0) {
        int sA = col[e];
        uint2 vA = *reinterpret_cast<const uint2*>(Xl + (size_t)sA * HID);
        a0 += bf2f((unsigned short)(vA.x & 0xffffu));
        a1 += bf2f((unsigned short)(vA.x >> 16));
        a2 += bf2f((unsigned short)(vA.y & 0xffffu));
        a3 += bf2f((unsigned short)(vA.y >> 16));
    }
    a0 += b0; a1 += b1; a2 += b2; a3 += b3;
    a0 += __shfl_xor(a0, 32, 64);
    a1 += __shfl_xor(a1, 32, 64);
    a2 += __shfl_xor(a2, 32, 64);
    a3 += __shfl_xor(a3, 32, 64);

    if (half == 0) {
        float inv = 1.0f / (float)max(end - start, 1);
        uint2 o;
        o.x = (unsigned int)f2bf(a0 * inv) | ((unsigned int)f2bf(a1 * inv) << 16);
        o.y = (unsigned int)f2bf(a2 * inv) | ((unsigned int)f2bf(a3 * inv) << 16);
        *reinterpret_cast<uint2*>(M + (size_t)wid * HID + l32 * 4) = o;
    }
}

// ---------------------------------------------------------------------------
// Single-edge-type MFMA SAGE (td): out = norm([mean|x]@Wt + bl), fp32 write.
// C/D layout: col = lane&15, row = (lane>>4)*4 + reg   [verified m89]
// ---------------------------------------------------------------------------
template <int CO>
__global__ __launch_bounds__(256) void sage_mfma(
    const unsigned short* __restrict__ Mb,
    const unsigned short* __restrict__ Xb,
    const unsigned short* __restrict__ Wt,
    const float* __restrict__ bl,
    float* __restrict__ H, int n)
{
    constexpr int NT = CO / 16;
    const int wave = threadIdx.x >> 6;
    const int lane = threadIdx.x & 63;
    const int r16 = lane & 15;
    const int chunk = lane >> 4;
    const int rowbase = blockIdx.x * 64 + wave * 16;
    if (rowbase >= n) return;

    const int arow = min(rowbase + r16, n - 1);
    const unsigned short* mrow = Mb + (size_t)arow * HID;
    const unsigned short* xrow = Xb + (size_t)arow * HID;

    bf16x8 a[8];
#pragma unroll
    for (int s = 0; s < 4; ++s) {
        a[s]     = *reinterpret_cast<const bf16x8*>(mrow + s * 32 + chunk * 8);
        a[4 + s] = *reinterpret_cast<const bf16x8*>(xrow + s * 32 + chunk * 8);
    }

    f32x4 acc[NT];
#pragma unroll
    for (int t = 0; t < NT; ++t) acc[t] = f32x4{0.f, 0.f, 0.f, 0.f};

#pragma unroll
    for (int t = 0; t < NT; ++t) {
        const unsigned short* wr_ = Wt + (size_t)(t * 16 + r16) * 256;
#pragma unroll
        for (int s = 0; s < 8; ++s) {
            bf16x8 b = *reinterpret_cast<const bf16x8*>(wr_ + s * 32 + chunk * 8);
            acc[t] = __builtin_amdgcn_mfma_f32_16x16x32_bf16(a[s], b, acc[t], 0, 0, 0);
        }
    }

    float ss[4] = {0.f, 0.f, 0.f, 0.f};
#pragma unroll
    for (int t = 0; t < NT; ++t) {
        float bias = bl[t * 16 + r16];
#pragma unroll
        for (int r = 0; r < 4; ++r) {
            acc[t][r] += bias;
            ss[r] += acc[t][r] * acc[t][r];
        }
    }
#pragma unroll
    for (int r = 0; r < 4; ++r)
#pragma unroll
        for (int m = 1; m < 16; m <<= 1)
            ss[r] += __shfl_xor(ss[r], m, 64);

#pragma unroll
    for (int r = 0; r < 4; ++r) {
        int node = rowbase + chunk * 4 + r;
        if (node < n) {
            float inv = 1.0f / fmaxf(sqrtf(ss[r]), 1e-12f);
#pragma unroll
            for (int t = 0; t < NT; ++t)
                H[(size_t)node * CO + t * 16 + r16] = acc[t][r] * inv;
        }
    }
}

// ---------------------------------------------------------------------------
// Dual-edge-type SAGE (dd + rd): H = norm(A-path) + norm(B-path), fp32 write.
// ---------------------------------------------------------------------------
template <int CO>
__global__ __launch_bounds__(256) void sage2_mfma(
    const unsigned short* __restrict__ MbA,
    const unsigned short* __restrict__ MbB,
    const unsigned short* __restrict__ Xb,
    const unsigned short* __restrict__ WtA,
    const unsigned short* __restrict__ WtB,
    const float* __restrict__ blA, const float* __restrict__ blB,
    float* __restrict__ H, int n)
{
    constexpr int NT = CO / 16;
    const int wave = threadIdx.x >> 6;
    const int lane = threadIdx.x & 63;
    const int r16 = lane & 15;
    const int chunk = lane >> 4;
    const int rowbase = blockIdx.x * 64 + wave * 16;
    if (rowbase >= n) return;

    const int arow = min(rowbase + r16, n - 1);
    const unsigned short* marow = MbA + (size_t)arow * HID;
    const unsigned short* mbrow = MbB + (size_t)arow * HID;
    const unsigned short* xrow  = Xb  + (size_t)arow * HID;

    bf16x8 aA[4], aB[4], ax[4];
#pragma unroll
    for (int s = 0; s < 4; ++s) {
        aA[s] = *reinterpret_cast<const bf16x8*>(marow + s * 32 + chunk * 8);
        aB[s] = *reinterpret_cast<const bf16x8*>(mbrow + s * 32 + chunk * 8);
        ax[s] = *reinterpret_cast<const bf16x8*>(xrow  + s * 32 + chunk * 8);
    }

    f32x4 accA[NT], accB[NT];
#pragma unroll
    for (int t = 0; t < NT; ++t) {
        accA[t] = f32x4{0.f, 0.f, 0.f, 0.f};
        accB[t] = f32x4{0.f, 0.f, 0.f, 0.f};
    }

#pragma unroll
    for (int t = 0; t < NT; ++t) {
        const unsigned short* wA = WtA + (size_t)(t * 16 + r16) * 256;
        const unsigned short* wB = WtB + (size_t)(t * 16 + r16) * 256;
#pragma unroll
        for (int s = 0; s < 4; ++s) {
            bf16x8 b0 = *reinterpret_cast<const bf16x8*>(wA + s * 32 + chunk * 8);
            accA[t] = __builtin_amdgcn_mfma_f32_16x16x32_bf16(aA[s], b0, accA[t], 0, 0, 0);
            bf16x8 b1 = *reinterpret_cast<const bf16x8*>(wA + HID + s * 32 + chunk * 8);
            accA[t] = __builtin_amdgcn_mfma_f32_16x16x32_bf16(ax[s], b1, accA[t], 0, 0, 0);
            bf16x8 b2 = *reinterpret_cast<const bf16x8*>(wB + s * 32 + chunk * 8);
            accB[t] = __builtin_amdgcn_mfma_f32_16x16x32_bf16(aB[s], b2, accB[t], 0, 0, 0);
            bf16x8 b3 = *reinterpret_cast<const bf16x8*>(wB + HID + s * 32 + chunk * 8);
            accB[t] = __builtin_amdgcn_mfma_f32_16x16x32_bf16(ax[s], b3, accB[t], 0, 0, 0);
        }
    }

    float ssA[4] = {0.f, 0.f, 0.f, 0.f};
    float ssB[4] = {0.f, 0.f, 0.f, 0.f};
#pragma unroll
    for (int t = 0; t < NT; ++t) {
        float biasA = blA[t * 16 + r16];
        float biasB = blB[t * 16 + r16];
#pragma unroll
        for (int r = 0; r < 4; ++r) {
            accA[t][r] += biasA;
            ssA[r] += accA[t][r] * accA[t][r];
            accB[t][r] += biasB;
            ssB[r] += accB[t][r] * accB[t][r];
        }
    }
#pragma unroll
    for (int r = 0; r < 4; ++r)
#pragma unroll
        for (int m = 1; m < 16; m <<= 1) {
            ssA[r] += __shfl_xor(ssA[r], m, 64);
            ssB[r] += __shfl_xor(ssB[r], m, 64);
        }

#pragma unroll
    for (int r = 0; r < 4; ++r) {
        int node = rowbase + chunk * 4 + r;
        if (node < n) {
            float invA = 1.0f / fmaxf(sqrtf(ssA[r]), 1e-12f);
            float invB = 1.0f / fmaxf(sqrtf(ssB[r]), 1e-12f);
#pragma unroll
            for (int t = 0; t < NT; ++t)
                H[(size_t)node * CO + t * 16 + r16] =
                    accA[t][r] * invA + accB[t][r] * invB;
        }
    }
}

// ---------------------------------------------------------------------------
// LayerNorm (+optional ReLU), one wave per row; fp32 in; bf16 or fp32 out.
// ---------------------------------------------------------------------------
template <int D, bool RELU, bool OUTBF>
__global__ __launch_bounds__(256) void ln_kernel(
    const float* __restrict__ X, const float* __restrict__ gg,
    const float* __restrict__ bb, void* __restrict__ outp, int n)
{
    constexpr int VPL = D / 64;
    int wid = (blockIdx.x * blockDim.x + threadIdx.x) >> 6;
    int lane = threadIdx.x & 63;
    if (wid >= n) return;

    float v[VPL], gv[VPL], bv[VPL];
    const float* xp = X + (size_t)wid * D + lane * VPL;
#pragma unroll
    for (int k = 0; k < VPL; ++k) {
        v[k] = xp[k];
        gv[k] = gg[lane * VPL + k];
        bv[k] = bb[lane * VPL + k];
    }
    float s = 0.f;
#pragma unroll
    for (int k = 0; k < VPL; ++k) s += v[k];
#pragma unroll
    for (int off = 32; off > 0; off >>= 1) s += __shfl_xor(s, off, 64);
    float m = s / D;
    float ss = 0.f;
#pragma unroll
    for (int k = 0; k < VPL; ++k) { float d = v[k] - m; ss += d * d; }
#pragma unroll
    for (int off = 32; off > 0; off >>= 1) ss += __shfl_xor(ss, off, 64);
    float rstd = rsqrtf(ss / D + 1e-5f);

    float y[VPL];
#pragma unroll
    for (int k = 0; k < VPL; ++k) {
        y[k] = gv[k] * (v[k] - m) * rstd + bv[k];
        if (RELU) y[k] = fmaxf(y[k], 0.f);
    }
    if (OUTBF) {
        unsigned short* op = (unsigned short*)outp + (size_t)wid * D + lane * VPL;
#pragma unroll
        for (int k = 0; k < VPL; ++k) op[k] = f2bf(y[k]);
    } else {
        float* op = (float*)outp + (size_t)wid * D + lane * VPL;
#pragma unroll
        for (int k = 0; k < VPL; ++k) op[k] = y[k];
    }
}

// ---------------------------------------------------------------------------
extern "C" void kernel_launch(void* const* d_in, const int* in_sizes, int n_in,
                              void* d_out, int out_size, void* d_ws, size_t ws_size,
                              hipStream_t stream)
{
    const int*   x_drug   = (const int*)d_in[0];
    const int*   x_dis    = (const int*)d_in[1];
    const float* emb_drug = (const float*)d_in[2];
    const float* emb_dis  = (const float*)d_in[3];
    const int*   src_dd   = (const int*)d_in[4];
    const int*   dst_dd   = (const int*)d_in[5];
    const int*   src_td   = (const int*)d_in[6];
    const int*   dst_td   = (const int*)d_in[7];
    const int*   src_rd   = (const int*)d_in[8];
    const int*   dst_rd   = (const int*)d_in[9];
    const float* Wl0_dd = (const float*)d_in[10];
    const float* bl0_dd = (const float*)d_in[11];
    const float* Wr0_dd = (const float*)d_in[12];
    const float* Wl0_td = (const float*)d_in[13];
    const float* bl0_td = (const float*)d_in[14];
    const float* Wr0_td = (const float*)d_in[15];
    const float* Wl0_rd = (const float*)d_in[16];
    const float* bl0_rd = (const float*)d_in[17];
    const float* Wr0_rd = (const float*)d_in[18];
    const float* Wl1_dd = (const float*)d_in[19];
    const float* bl1_dd = (const float*)d_in[20];
    const float* Wr1_dd = (const float*)d_in[21];
    const float* Wl1_td = (const float*)d_in[22];
    const float* bl1_td = (const float*)d_in[23];
    const float* Wr1_td = (const float*)d_in[24];
    const float* Wl1_rd = (const float*)d_in[25];
    const float* bl1_rd = (const float*)d_in[26];
    const float* Wr1_rd = (const float*)d_in[27];
    const float* g0_drug = (const float*)d_in[28];
    const float* b0_drug = (const float*)d_in[29];
    const float* g0_dis  = (const float*)d_in[30];
    const float* b0_dis  = (const float*)d_in[31];
    const float* g1_drug = (const float*)d_in[32];
    const float* b1_drug = (const float*)d_in[33];
    const float* g1_dis  = (const float*)d_in[34];
    const float* b1_dis  = (const float*)d_in[35];

    // ---------------- workspace layout ----------------
    char* wp = (char*)d_ws;
    auto alloc = [&](size_t bytes) { char* p = wp; wp += (bytes + 255) & ~size_t(255); return p; };

    unsigned short* hd0  = (unsigned short*)alloc((size_t)ND * HID * 2);
    unsigned short* hz0  = (unsigned short*)alloc((size_t)NZ * HID * 2);
    unsigned short* hd1b = (unsigned short*)alloc((size_t)ND * HID * 2);
    unsigned short* hz1b = (unsigned short*)alloc((size_t)NZ * HID * 2);
    unsigned short* meanA= (unsigned short*)alloc((size_t)ND * HID * 2);
    unsigned short* meanB= (unsigned short*)alloc((size_t)ND * HID * 2);
    unsigned short* meanC= (unsigned short*)alloc((size_t)NZ * HID * 2);
    float* hd1f = (float*)alloc((size_t)ND * HID * 4);
    float* hz1f = (float*)alloc((size_t)NZ * HID * 4);
    unsigned short* Wt0_dd = (unsigned short*)alloc((size_t)HID * 256 * 2);
    unsigned short* Wt0_rd = (unsigned short*)alloc((size_t)HID * 256 * 2);
    unsigned short* Wt0_td = (unsigned short*)alloc((size_t)HID * 256 * 2);
    unsigned short* Wt1_dd = (unsigned short*)alloc((size_t)OUTD * 256 * 2);
    unsigned short* Wt1_rd = (unsigned short*)alloc((size_t)OUTD * 256 * 2);
    unsigned short* Wt1_td = (unsigned short*)alloc((size_t)OUTD * 256 * 2);
    int* offs_dd = (int*)alloc((ND + 1) * 4);
    int* offs_rd = (int*)alloc((ND + 1) * 4);
    int* offs_td = (int*)alloc((NZ + 1) * 4);
    int* col_dd  = (int*)alloc((size_t)E * 4);
    int* col_rd  = (int*)alloc((size_t)E * 4);
    int* col_td  = (int*)alloc((size_t)E * 4);
    // contiguous count region (one memset covers all three)
    int* cnt_dd  = (int*)alloc(((size_t)(ND + 1) + (ND + 1) + (NZ + 1)) * 4);
    int* cnt_rd  = cnt_dd + (ND + 1);
    int* cnt_td  = cnt_rd + (ND + 1);
    int* cur_dd  = (int*)alloc((ND + 1) * 4);
    int* cur_rd  = (int*)alloc((ND + 1) * 4);
    int* cur_td  = (int*)alloc((NZ + 1) * 4);
    int* part    = (int*)alloc(3 * 64 * 4);

    float* outD = (float*)d_out;
    float* outZ = outD + (size_t)ND * OUTD;

    // ---------------- independent prep ----------------
    hipMemsetAsync(cnt_dd, 0, ((size_t)(ND + 1) + (ND + 1) + (NZ + 1)) * 4, stream);

    gather_all<<<ceil_div((ND + NZ) * 32, 256), 256, 0, stream>>>(
        emb_drug, x_drug, emb_dis, x_dis, hd0, hz0);

    PrepArgs pa;
    pa.wl[0] = Wl0_dd; pa.wr[0] = Wr0_dd; pa.wt[0] = Wt0_dd; pa.co[0] = HID;
    pa.wl[1] = Wl0_rd; pa.wr[1] = Wr0_rd; pa.wt[1] = Wt0_rd; pa.co[1] = HID;
    pa.wl[2] = Wl0_td; pa.wr[2] = Wr0_td; pa.wt[2] = Wt0_td; pa.co[2] = HID;
    pa.wl[3] = Wl1_dd; pa.wr[3] = Wr1_dd; pa.wt[3] = Wt1_dd; pa.co[3] = OUTD;
    pa.wl[4] = Wl1_rd; pa.wr[4] = Wr1_rd; pa.wt[4] = Wt1_rd; pa.co[4] = OUTD;
    pa.wl[5] = Wl1_td; pa.wr[5] = Wr1_td; pa.wt[5] = Wt1_td; pa.co[5] = OUTD;
    pa.boff[0] = 0;
    for (int s = 0; s < 6; ++s) pa.boff[s + 1] = pa.boff[s] + pa.co[s];
    prep_all<<<pa.boff[6], 256, 0, stream>>>(pa);

    // ---------------- CSR build (XCD-range-partitioned) ----------------
    hist8<<<3 * NXCD * HISTC, 256, 0, stream>>>(
        dst_dd, dst_rd, dst_td, cnt_dd, cnt_rd, cnt_td);
    scan_part3<<<2 * NB_D + NB_Z, 256, 0, stream>>>(cnt_dd, cnt_rd, cnt_td, part);
    scan_small3<<<3, 64, 0, stream>>>(part, offs_dd, offs_rd, offs_td);
    scan_write3<<<2 * NB_D + NB_Z, 256, 0, stream>>>(
        cnt_dd, cnt_rd, cnt_td, part, offs_dd, offs_rd, offs_td, cur_dd, cur_rd, cur_td);
    fill8<<<3 * NXCD * FILLC, 256, 0, stream>>>(
        src_dd, dst_dd, src_rd, dst_rd, src_td, dst_td,
        cur_dd, cur_rd, cur_td, col_dd, col_rd, col_td);

    // ---------------- layer 0 ----------------
    agg3<<<ceil_div((2 * ND + NZ) * 64, 256), 256, 0, stream>>>(
        offs_dd, col_dd, hd0, meanA, ND,
        offs_rd, col_rd, hz0, meanB, ND,
        offs_td, col_td, hd0, meanC, NZ);
    sage2_mfma<HID><<<ceil_div(ND, 64), 256, 0, stream>>>(
        meanA, meanB, hd0, Wt0_dd, Wt0_rd, bl0_dd, bl0_rd, hd1f, ND);
    sage_mfma<HID><<<ceil_div(NZ, 64), 256, 0, stream>>>(
        meanC, hz0, Wt0_td, bl0_td, hz1f, NZ);

    ln_kernel<HID, true, true><<<ceil_div(ND, 4), 256, 0, stream>>>(hd1f, g0_drug, b0_drug, hd1b, ND);
    ln_kernel<HID, true, true><<<ceil_div(NZ, 4), 256, 0, stream>>>(hz1f, g0_dis, b0_dis, hz1b, NZ);

    // ---------------- layer 1 ----------------
    agg3<<<ceil_div((2 * ND + NZ) * 64, 256), 256, 0, stream>>>(
        offs_dd, col_dd, hd1b, meanA, ND,
        offs_rd, col_rd, hz1b, meanB, ND,
        offs_td, col_td, hd1b, meanC, NZ);
    sage2_mfma<OUTD><<<ceil_div(ND, 64), 256, 0, stream>>>(
        meanA, meanB, hd1b, Wt1_dd, Wt1_rd, bl1_dd, bl1_rd, outD, ND);
    sage_mfma<OUTD><<<ceil_div(NZ, 64), 256, 0, stream>>>(
        meanC, hz1b, Wt1_td, bl1_td, outZ, NZ);

    ln_kernel<OUTD, false, false><<<ceil_div(ND, 4), 256, 0, stream>>>(outD, g1_drug, b1_drug, outD, ND);
    ln_kernel<OUTD, false, false><<<ceil_div(NZ, 4), 256, 0, stream>>>(outZ, g1_dis, b1_dis, outZ, NZ);
}